// Round 13
// baseline (341.447 us; speedup 1.0000x reference)
//
#include <hip/hip_runtime.h>
#include <hip/hip_bf16.h>
#include <cstdint>

#define B_ 16
#define N_ 1024
#define T_ 12
#define HD 64
#define BN_ (B_*N_)     // 16384
#define BNT (B_*N_*T_)  // 196608
#define TD (T_*HD)      // 768

typedef __attribute__((ext_vector_type(8))) short short8;
typedef __attribute__((ext_vector_type(4))) float f32x4;

#define MFMA16(a,b,c) __builtin_amdgcn_mfma_f32_16x16x32_bf16(a,b,c,0,0,0)

__device__ __forceinline__ float sigmoidf_(float x) { return 1.f / (1.f + __expf(-x)); }

__device__ __forceinline__ unsigned short f2bf(float f) {
  __hip_bfloat16 h = __float2bfloat16(f);
  return __builtin_bit_cast(unsigned short, h);
}
__device__ __forceinline__ unsigned int f2bf2(float lo, float hi) {
  return (unsigned int)f2bf(lo) | ((unsigned int)f2bf(hi) << 16);
}
__device__ __forceinline__ float bf2f(unsigned short h) {
  unsigned int u = ((unsigned int)h) << 16;
  return __uint_as_float(u);
}

// ---------------- reductions ----------------
__device__ __forceinline__ float blkRedMax(float v, float* red) {
  #pragma unroll
  for (int off = 32; off >= 1; off >>= 1) v = fmaxf(v, __shfl_xor(v, off));
  int w = threadIdx.x >> 6;
  if ((threadIdx.x & 63) == 0) red[w] = v;
  __syncthreads();
  v = fmaxf(fmaxf(red[0], red[1]), fmaxf(red[2], red[3]));
  __syncthreads();
  return v;
}
__device__ __forceinline__ float blkRedSum(float v, float* red) {
  #pragma unroll
  for (int off = 32; off >= 1; off >>= 1) v += __shfl_xor(v, off);
  int w = threadIdx.x >> 6;
  if ((threadIdx.x & 63) == 0) red[w] = v;
  __syncthreads();
  v = red[0] + red[1] + red[2] + red[3];
  __syncthreads();
  return v;
}

// ---------------- K-wprep-e2 ----------------
__global__ void k_wprep_e2(const float* __restrict__ w1, const float* __restrict__ w2,
                           const float* __restrict__ gcw, unsigned short* __restrict__ W)
{
  int t = blockIdx.x*256 + threadIdx.x;   // 64*256 = 16384
  if (t < 4096)       W[t] = f2bf(w1[t]);
  else if (t < 12288) W[t] = f2bf(w2[t-4096]);
  else {
    int r = t - 12288, e = r >> 6, d = r & 63;
    W[12288 + e*64 + d] = f2bf(gcw[d*64 + e]);
  }
}

// ---------------- K-wprep3 ----------------
__global__ void k_wprep3(const float* __restrict__ wi,
                         const float* __restrict__ w1m, const float* __restrict__ w1g,
                         const float* __restrict__ w2m, const float* __restrict__ w2g,
                         const float* __restrict__ wfc, unsigned short* __restrict__ W)
{
  int t = blockIdx.x*256 + threadIdx.x;  // 96*256 = 24576
  {
    int o = t / 192, k = t - o*192, tap = k >> 6, i = k & 63;
    W[o*192 + k] = f2bf(wi[(o*64 + i)*3 + tap]);
  }
  if (t < 12288) {
    int o = t / 192, k = t - o*192, tap = k >> 6, i = k & 63;
    int src = (o*64 + i)*3 + tap;
    W[24576 + o*192 + k]      = f2bf(w1m[src]);
    W[24576 + (64+o)*192 + k] = f2bf(w1g[src]);
    W[49152 + o*192 + k]      = f2bf(w2m[src]);
    W[49152 + (64+o)*192 + k] = f2bf(w2g[src]);
  }
  if (t < 8192) W[73728 + t] = f2bf(wfc[t]);
}

// ---------------- K-wprep4 ----------------
__global__ void k_wprep4(const float* __restrict__ wq, const float* __restrict__ wk,
                         const float* __restrict__ wv, const float* __restrict__ wo,
                         const float* __restrict__ f1w, const float* __restrict__ f2w,
                         unsigned short* __restrict__ W)
{
  int t = blockIdx.x*256 + threadIdx.x;  // 192*256 = 49152
  if (t < 4096)        W[t] = f2bf(wq[t]);
  else if (t < 8192)   W[t] = f2bf(wk[t-4096]);
  else if (t < 12288)  W[t] = f2bf(wv[t-8192]);
  else if (t < 16384)  W[t] = f2bf(wo[t-12288]);
  else if (t < 32768)  W[t] = f2bf(f1w[t-16384]);
  else                 W[t] = f2bf(f2w[t-32768]);
}

// ---------------- K1: embed + gfs_fc + GLU + (x @ gc_weight), full MFMA ----------------
__global__ __launch_bounds__(256) void k_embed3(
    const float* __restrict__ flow, const int* __restrict__ day, const int* __restrict__ week,
    const float* __restrict__ semb, const float* __restrict__ demb, const float* __restrict__ wemb,
    const unsigned short* __restrict__ wTe, const float* __restrict__ b1,
    const float* __restrict__ b2,
    unsigned short* __restrict__ outw)
{
  __shared__ unsigned short sEa[128*72];
  __shared__ unsigned short sEb[128*72];
  const unsigned short* W1  = wTe;
  const unsigned short* W2  = wTe + 4096;
  const unsigned short* GcT = wTe + 12288;

  int tid = threadIdx.x, lane = tid & 63, w = tid >> 6;
  int l15 = lane & 15, l4 = lane >> 4;
  int row0 = blockIdx.x * 128;

  for (int i = tid; i < 8192; i += 256) {
    int r = i >> 6, c = i & 63;
    int row = row0 + r;
    int n = (row / T_) & (N_-1);
    float val;
    if (c == 0)      val = flow[row];
    else if (c < 33) val = semb[n*32 + (c-1)];
    else if (c < 49) val = demb[day[row]*16 + (c-33)];
    else             val = wemb[week[row]*15 + (c-49)];
    sEa[r*72 + c] = f2bf(val);
  }
  __syncthreads();

  {
    f32x4 acc[8] = {};
    #pragma unroll
    for (int ks = 0; ks < 2; ++ks) {
      short8 bf = *(const short8*)&W1[(w*16 + l15)*64 + ks*32 + l4*8];
      #pragma unroll
      for (int mt = 0; mt < 8; ++mt) {
        short8 af = *(const short8*)&sEa[(mt*16 + l15)*72 + ks*32 + l4*8];
        acc[mt] = MFMA16(af, bf, acc[mt]);
      }
    }
    float bias = b1[w*16 + l15];
    #pragma unroll
    for (int mt = 0; mt < 8; ++mt)
      #pragma unroll
      for (int r = 0; r < 4; ++r)
        sEb[(mt*16 + l4*4 + r)*72 + w*16 + l15] = f2bf(acc[mt][r] + bias);
  }
  __syncthreads();

  {
    f32x4 alo[8] = {}, ahi[8] = {};
    #pragma unroll
    for (int ks = 0; ks < 2; ++ks) {
      short8 blo = *(const short8*)&W2[(size_t)(w*16 + l15)*64 + ks*32 + l4*8];
      short8 bhi = *(const short8*)&W2[(size_t)(64 + w*16 + l15)*64 + ks*32 + l4*8];
      #pragma unroll
      for (int mt = 0; mt < 8; ++mt) {
        short8 af = *(const short8*)&sEb[(mt*16 + l15)*72 + ks*32 + l4*8];
        alo[mt] = MFMA16(af, blo, alo[mt]);
        ahi[mt] = MFMA16(af, bhi, ahi[mt]);
      }
    }
    float blov = b2[w*16 + l15], bhiv = b2[64 + w*16 + l15];
    #pragma unroll
    for (int mt = 0; mt < 8; ++mt)
      #pragma unroll
      for (int r = 0; r < 4; ++r) {
        float v = (alo[mt][r] + blov) * sigmoidf_(ahi[mt][r] + bhiv);
        sEa[(mt*16 + l4*4 + r)*72 + w*16 + l15] = f2bf(v);
      }
  }
  __syncthreads();

  {
    f32x4 acc[8] = {};
    #pragma unroll
    for (int ks = 0; ks < 2; ++ks) {
      short8 bf = *(const short8*)&GcT[(w*16 + l15)*64 + ks*32 + l4*8];
      #pragma unroll
      for (int mt = 0; mt < 8; ++mt) {
        short8 af = *(const short8*)&sEa[(mt*16 + l15)*72 + ks*32 + l4*8];
        acc[mt] = MFMA16(af, bf, acc[mt]);
      }
    }
    #pragma unroll
    for (int mt = 0; mt < 8; ++mt)
      #pragma unroll
      for (int r = 0; r < 4; ++r)
        outw[(size_t)(row0 + mt*16 + l4*4 + r)*64 + w*16 + l15] = f2bf(acc[mt][r]);
  }
}

// ---------------- K2: A = softmax(relu(A1),1) + softmax(relu(A2),1), bf16 out ------------
__global__ __launch_bounds__(256) void k_aprep(
    const float* __restrict__ A1, const float* __restrict__ A2, unsigned short* __restrict__ Aout)
{
  __shared__ float red[4];
  int m = blockIdx.x, tid = threadIdx.x;
  float mx0, is0, mx1, is1;
  {
    const float* src = A1 + (size_t)m*N_;
    float mx = 0.f;
    for (int i = tid; i < N_; i += 256) mx = fmaxf(mx, fmaxf(src[i], 0.f));
    mx = blkRedMax(mx, red);
    float s = 0.f;
    for (int i = tid; i < N_; i += 256) s += __expf(fmaxf(src[i], 0.f) - mx);
    s = blkRedSum(s, red);
    mx0 = mx; is0 = 1.f / s;
  }
  {
    const float* src = A2 + (size_t)m*N_;
    float mx = 0.f;
    for (int i = tid; i < N_; i += 256) mx = fmaxf(mx, fmaxf(src[i], 0.f));
    mx = blkRedMax(mx, red);
    float s = 0.f;
    for (int i = tid; i < N_; i += 256) s += __expf(fmaxf(src[i], 0.f) - mx);
    s = blkRedSum(s, red);
    mx1 = mx; is1 = 1.f / s;
  }
  const float* s1 = A1 + (size_t)m*N_;
  const float* s2 = A2 + (size_t)m*N_;
  for (int i = tid; i < N_; i += 256) {
    float v1 = __expf(fmaxf(s1[i], 0.f) - mx0) * is0;
    float v2 = __expf(fmaxf(s2[i], 0.f) - mx1) * is1;
    Aout[(size_t)m*N_ + i] = f2bf(v1 + v2);
  }
}

// ---------------- K3: bf16 MFMA batched GEMM ----------------
template<int RELU, int OB16>
__global__ __launch_bounds__(256) void k_gemm_mfma(
    const unsigned short* __restrict__ A, const unsigned short* __restrict__ X,
    void* __restrict__ C, int K, int P)
{
  __shared__ unsigned short sA[128*40];
  __shared__ unsigned short sB[128*40];
  int tid = threadIdx.x, lane = tid & 63, wid = tid >> 6;
  int M = gridDim.y * 128;
  int b = blockIdx.z;
  const unsigned short* Xb = X + (size_t)b*K*P;
  int m0 = blockIdx.y*128, p0 = blockIdx.x*128;
  int wr = wid >> 1, wc = wid & 1;

  f32x4 acc[4][4] = {};

  for (int k0 = 0; k0 < K; k0 += 32) {
    #pragma unroll
    for (int pass = 0; pass < 2; ++pass) {
      int r = (tid >> 2) + 64*pass, kk = (tid & 3)*8;
      short8 v = *(const short8*)&A[(size_t)(m0+r)*K + k0 + kk];
      *(short8*)&sA[r*40 + kk] = v;
    }
    #pragma unroll
    for (int pass = 0; pass < 4; ++pass) {
      int p  = (tid & 63) + 64*(pass & 1);
      int k4 = (tid >> 6)*4 + 16*(pass >> 1);
      ushort4 h;
      h.x = Xb[(size_t)(k0+k4+0)*P + p0 + p];
      h.y = Xb[(size_t)(k0+k4+1)*P + p0 + p];
      h.z = Xb[(size_t)(k0+k4+2)*P + p0 + p];
      h.w = Xb[(size_t)(k0+k4+3)*P + p0 + p];
      *(ushort4*)&sB[p*40 + k4] = h;
    }
    __syncthreads();
    short8 af[4], bf[4];
    #pragma unroll
    for (int f = 0; f < 4; ++f) {
      af[f] = *(const short8*)&sA[(wr*64 + f*16 + (lane & 15))*40 + (lane >> 4)*8];
      bf[f] = *(const short8*)&sB[(wc*64 + f*16 + (lane & 15))*40 + (lane >> 4)*8];
    }
    #pragma unroll
    for (int fm = 0; fm < 4; ++fm)
      #pragma unroll
      for (int fn = 0; fn < 4; ++fn)
        acc[fm][fn] = MFMA16(af[fm], bf[fn], acc[fm][fn]);
    __syncthreads();
  }
  #pragma unroll
  for (int fm = 0; fm < 4; ++fm) {
    int row = m0 + wr*64 + fm*16 + (lane >> 4)*4;
    #pragma unroll
    for (int fn = 0; fn < 4; ++fn) {
      int col = p0 + wc*64 + fn*16 + (lane & 15);
      #pragma unroll
      for (int r = 0; r < 4; ++r) {
        float v = acc[fm][fn][r];
        if (RELU) v = fmaxf(v, 0.f);
        if (OB16) {
          unsigned short* Cb = (unsigned short*)C + (size_t)b*M*P;
          Cb[(size_t)(row + r)*P + col] = f2bf(v);
        } else {
          float* Cb = (float*)C + (size_t)b*M*P;
          Cb[(size_t)(row + r)*P + col] = v;
        }
      }
    }
  }
}

// ---------------- K5: ds temporal-conv block, MFMA, 8 bn per block; bf16 out (in-place) ----
__global__ __launch_bounds__(256) void k_ds3(
    const unsigned short* xds,
    const unsigned short* __restrict__ Wall,
    const float* __restrict__ bi,
    const float* __restrict__ b1m, const float* __restrict__ b1g,
    const float* __restrict__ b2m, const float* __restrict__ b2g,
    const float* __restrict__ bfc,
    unsigned short* outg)
{
  __shared__ unsigned short smem[36352];
  unsigned short* X_lds  = smem;               // [8][14][72]
  unsigned short* xi_lds = smem + 8064;        // [8][14][136]
  unsigned short* fu_lds = smem + 23296;       // [96][136]
  const unsigned short* WiB  = Wall;
  const unsigned short* Wg1B = Wall + 24576;
  const unsigned short* Wg2B = Wall + 49152;
  const unsigned short* WfB  = Wall + 73728;

  int tid = threadIdx.x, lane = tid & 63, wid = tid >> 6;
  int l15 = lane & 15, l4 = lane >> 4;
  int bn0 = blockIdx.x * 8;

  for (int i = tid; i < 8*2*72; i += 256) {
    int g = i / 144, r = i - g*144;
    int tp = (r < 72) ? 0 : 13, c = (r < 72) ? r : r - 72;
    X_lds[(g*14 + tp)*72 + c] = 0;
  }
  for (int i = tid; i < 8*2*136; i += 256) {
    int g = i / 272, r = i - g*272;
    int tp = (r < 136) ? 0 : 13, c = (r < 136) ? r : r - 136;
    xi_lds[(g*14 + tp)*136 + c] = 0;
  }
  for (int i = tid; i < 768; i += 256) {
    int g = i / 96, rem = i - g*96, t = rem >> 3, i8 = rem & 7;
    short8 v = *(const short8*)&xds[(size_t)(bn0+g)*768 + t*64 + i8*8];
    *(short8*)&X_lds[(g*14 + t + 1)*72 + i8*8] = v;
  }
  __syncthreads();

  int ga[6], ta[6];
  #pragma unroll
  for (int mt = 0; mt < 6; ++mt) {
    int r = mt*16 + l15;
    ga[mt] = r / 12; ta[mt] = r - ga[mt]*12;
  }

  {
    f32x4 acc1[6][2] = {};
    int nb = wid*2;
    #pragma unroll
    for (int ks = 0; ks < 6; ++ks) {
      int tap = ks >> 1, i0 = (ks & 1)*32;
      short8 af[6];
      #pragma unroll
      for (int mt = 0; mt < 6; ++mt)
        af[mt] = *(const short8*)&X_lds[(ga[mt]*14 + ta[mt] + tap)*72 + i0 + l4*8];
      short8 bf0 = *(const short8*)&WiB[(size_t)((nb  )*16 + l15)*192 + ks*32 + l4*8];
      short8 bf1 = *(const short8*)&WiB[(size_t)((nb+1)*16 + l15)*192 + ks*32 + l4*8];
      #pragma unroll
      for (int mt = 0; mt < 6; ++mt) {
        acc1[mt][0] = MFMA16(af[mt], bf0, acc1[mt][0]);
        acc1[mt][1] = MFMA16(af[mt], bf1, acc1[mt][1]);
      }
    }
    #pragma unroll
    for (int nn = 0; nn < 2; ++nn) {
      int o = (nb+nn)*16 + l15;
      float bv = bi[o];
      #pragma unroll
      for (int mt = 0; mt < 6; ++mt) {
        #pragma unroll
        for (int reg = 0; reg < 4; ++reg) {
          int r = mt*16 + l4*4 + reg;
          int g = r / 12, t = r - g*12;
          xi_lds[(g*14 + t + 1)*136 + o] = f2bf(acc1[mt][nn][reg] + bv);
        }
      }
    }
  }
  __syncthreads();

  #pragma unroll
  for (int h = 0; h < 2; ++h) {
    const unsigned short* Wg = h ? Wg2B : Wg1B;
    f32x4 am[6] = {}, ag[6] = {};
    #pragma unroll
    for (int ks = 0; ks < 6; ++ks) {
      int tap = ks >> 1, i0 = (ks & 1)*32;
      short8 af[6];
      #pragma unroll
      for (int mt = 0; mt < 6; ++mt)
        af[mt] = *(const short8*)&xi_lds[(ga[mt]*14 + ta[mt] + tap)*136 + h*64 + i0 + l4*8];
      short8 bm = *(const short8*)&Wg[(size_t)(wid*16 + l15)*192 + ks*32 + l4*8];
      short8 bg = *(const short8*)&Wg[(size_t)((wid+4)*16 + l15)*192 + ks*32 + l4*8];
      #pragma unroll
      for (int mt = 0; mt < 6; ++mt) {
        am[mt] = MFMA16(af[mt], bm, am[mt]);
        ag[mt] = MFMA16(af[mt], bg, ag[mt]);
      }
    }
    int o = wid*16 + l15;
    float bmv = (h ? b2m : b1m)[o];
    float bgv = (h ? b2g : b1g)[o];
    #pragma unroll
    for (int mt = 0; mt < 6; ++mt) {
      #pragma unroll
      for (int reg = 0; reg < 4; ++reg) {
        int r = mt*16 + l4*4 + reg;
        int g = r / 12, t = r - g*12;
        float pm = am[mt][reg] + bmv;
        float pg = ag[mt][reg] + bgv;
        float po = pm * sigmoidf_(pg);
        float xi = bf2f(xi_lds[(g*14 + t + 1)*136 + h*64 + o]);
        fu_lds[r*136 + h*64 + o] = f2bf(fmaxf(po + xi, 0.f));
      }
    }
  }
  __syncthreads();

  {
    f32x4 a3[6] = {};
    #pragma unroll
    for (int ks = 0; ks < 4; ++ks) {
      short8 af = *(const short8*)&WfB[(size_t)(wid*16 + l15)*128 + ks*32 + l4*8];
      #pragma unroll
      for (int nt = 0; nt < 6; ++nt) {
        short8 bf = *(const short8*)&fu_lds[(nt*16 + l15)*136 + ks*32 + l4*8];
        a3[nt] = MFMA16(af, bf, a3[nt]);
      }
    }
    int e0 = wid*16 + l4*4;
    float4 bb = *(const float4*)&bfc[e0];
    #pragma unroll
    for (int nt = 0; nt < 6; ++nt) {
      uint2 vv;
      vv.x = f2bf2(a3[nt][0] + bb.x, a3[nt][1] + bb.y);
      vv.y = f2bf2(a3[nt][2] + bb.z, a3[nt][3] + bb.w);
      *(uint2*)&outg[((size_t)(bn0 + ga[nt])*12 + ta[nt])*64 + e0] = vv;
    }
  }
}

// ---------------- K6: attention + FFN + 2x LN, full MFMA, 8 bn / 512 thr per block ------
// Single-barrier LN (part[row][wn] + redundant per-thread stats); P via shfl (no atts).
__global__ __launch_bounds__(512) void k_attn4(
    const unsigned short* __restrict__ xg,     // bf16 [BN][12][64]
    const unsigned short* __restrict__ Wat,
    const float* __restrict__ bq, const float* __restrict__ bk, const float* __restrict__ bv,
    const float* __restrict__ bo,
    const float* __restrict__ f1b, const float* __restrict__ f2b,
    const float* __restrict__ g1, const float* __restrict__ be1,
    const float* __restrict__ g2, const float* __restrict__ be2,
    unsigned short* __restrict__ outg)
{
  __shared__ unsigned short su[33792];
  __shared__ float part1[96][4];
  __shared__ float part2[96][4];
  unsigned short* Ybuf = su;            // [96][72]
  unsigned short* Qkv  = su + 6912;     // [96][216]
  unsigned short* Hb   = su + 6912;     // [96][280] (union with Qkv)

  const unsigned short* Wqkv = Wat;
  const unsigned short* Wo   = Wat + 12288;
  const unsigned short* F1   = Wat + 16384;
  const unsigned short* F2   = Wat + 32768;

  int tid = threadIdx.x, lane = tid & 63, w = tid >> 6;
  int l15 = lane & 15, l4 = lane >> 4;
  int wn = w & 3, wm = w >> 2;
  size_t base = (size_t)blockIdx.x * 8 * 768;

  for (int i = tid; i < 768; i += 512) {
    int r = i >> 3, c = i & 7;
    *(short8*)&Ybuf[r*72 + c*8] = *(const short8*)&xg[base + r*64 + c*8];
  }
  __syncthreads();

  // ---- QKV GEMM: Qkv[96][192] ----
  {
    f32x4 acc[3][3] = {};
    #pragma unroll
    for (int ks = 0; ks < 2; ++ks) {
      short8 af[3];
      #pragma unroll
      for (int mi = 0; mi < 3; ++mi)
        af[mi] = *(const short8*)&Ybuf[((wm*3+mi)*16 + l15)*72 + ks*32 + l4*8];
      #pragma unroll
      for (int ni = 0; ni < 3; ++ni) {
        int nt = wn*3 + ni;
        short8 bf = *(const short8*)&Wqkv[(size_t)(nt*16 + l15)*64 + ks*32 + l4*8];
        #pragma unroll
        for (int mi = 0; mi < 3; ++mi)
          acc[mi][ni] = MFMA16(af[mi], bf, acc[mi][ni]);
      }
    }
    #pragma unroll
    for (int ni = 0; ni < 3; ++ni) {
      int col = (wn*3+ni)*16 + l15;
      float bias = col < 64 ? bq[col] : (col < 128 ? bk[col-64] : bv[col-128]);
      #pragma unroll
      for (int mi = 0; mi < 3; ++mi)
        #pragma unroll
        for (int r = 0; r < 4; ++r)
          Qkv[((wm*3+mi)*16 + l4*4 + r)*216 + col] = f2bf(acc[mi][ni][r] + bias);
    }
  }
  __syncthreads();

  // ---- attention: wave w owns bn w; P redistributed via shfl; o -> Qkv q-region ----
  {
    int rb = w*12;
    int src0 = (l15 + 32*l4) & 63;
    int src1 = (src0 + 16) & 63;
    #pragma unroll
    for (int h = 0; h < 4; ++h) {
      short8 kf = {}, qf = {};
      if (l4 < 2) {
        kf = *(const short8*)&Qkv[(rb + l15)*216 + 64 + h*16 + l4*8];
        qf = *(const short8*)&Qkv[(rb + l15)*216 +      h*16 + l4*8];
      }
      f32x4 sc = {};
      sc = MFMA16(kf, qf, sc);
      float e[4]; float mx = -3e38f;
      #pragma unroll
      for (int r = 0; r < 4; ++r) {
        float v = (l4 == 3) ? -3e38f : sc[r]*0.25f;
        e[r] = v; mx = fmaxf(mx, v);
      }
      mx = fmaxf(mx, __shfl_xor(mx, 16));
      mx = fmaxf(mx, __shfl_xor(mx, 32));
      float s = 0.f;
      #pragma unroll
      for (int r = 0; r < 4; ++r) { e[r] = __expf(e[r] - mx); s += e[r]; }
      s += __shfl_xor(s, 16); s += __shfl_xor(s, 32);
      float inv = 1.f/s;
      int pk0 = (int)f2bf2(e[0]*inv, e[1]*inv);
      int pk1 = (int)f2bf2(e[2]*inv, e[3]*inv);
      // redistribute: lane(l15,l4) needs P[s=l4*8+j][l15] = pk from lanes l15+32*l4, +16
      int a0 = __shfl(pk0, src0), b0 = __shfl(pk1, src0);
      int c0 = __shfl(pk0, src1), d0 = __shfl(pk1, src1);
      short8 aaf = {};
      if (l4 < 2) {
        uint4 u = make_uint4((unsigned)a0, (unsigned)b0, (unsigned)c0, (unsigned)d0);
        aaf = __builtin_bit_cast(short8, u);
      }
      short8 vf = {};
      if (l4 < 2) {
        #pragma unroll
        for (int j = 0; j < 8; ++j) {
          int s_ = l4*8 + j;
          vf[j] = (s_ < 12) ? (short)Qkv[(rb + s_)*216 + 128 + h*16 + l15] : (short)0;
        }
      }
      f32x4 o = {};
      o = MFMA16(aaf, vf, o);
      if (l4 < 3) {
        #pragma unroll
        for (int r = 0; r < 4; ++r)
          Qkv[(rb + l4*4 + r)*216 + h*16 + l15] = f2bf(o[r]);   // q-region (dead)
      }
    }
  }
  __syncthreads();

  // ---- WO GEMM + residual(LDS) + LN1 (single barrier) ----
  {
    f32x4 zacc[3] = {};
    #pragma unroll
    for (int ks = 0; ks < 2; ++ks) {
      short8 bf = *(const short8*)&Wo[(size_t)(wn*16 + l15)*64 + ks*32 + l4*8];
      #pragma unroll
      for (int mi = 0; mi < 3; ++mi) {
        short8 af = *(const short8*)&Qkv[((wm*3+mi)*16 + l15)*216 + ks*32 + l4*8];
        zacc[mi] = MFMA16(af, bf, zacc[mi]);
      }
    }
    int col = wn*16 + l15;
    float bias = bo[col];
    #pragma unroll
    for (int mi = 0; mi < 3; ++mi)
      #pragma unroll
      for (int r = 0; r < 4; ++r) {
        int row = (wm*3+mi)*16 + l4*4 + r;
        float z = zacc[mi][r] + bias + bf2f(Ybuf[row*72 + col]);
        zacc[mi][r] = z;
        float s1 = z, s2 = z*z;
        #pragma unroll
        for (int off = 1; off <= 8; off <<= 1) { s1 += __shfl_xor(s1, off); s2 += __shfl_xor(s2, off); }
        if (l15 == 0) { part1[row][wn] = s1; part2[row][wn] = s2; }
      }
    __syncthreads();
    float gv = g1[col], bvv = be1[col];
    #pragma unroll
    for (int mi = 0; mi < 3; ++mi)
      #pragma unroll
      for (int r = 0; r < 4; ++r) {
        int row = (wm*3+mi)*16 + l4*4 + r;
        float4 p1 = *(const float4*)part1[row];
        float4 p2 = *(const float4*)part2[row];
        float mu  = (p1.x + p1.y + p1.z + p1.w) * (1.f/64.f);
        float var = (p2.x + p2.y + p2.z + p2.w) * (1.f/64.f) - mu*mu;
        Ybuf[row*72 + col] = f2bf((zacc[mi][r] - mu) * rsqrtf(var + 1e-5f) * gv + bvv);
      }
  }
  __syncthreads();

  // ---- FF1: Hb[96][256] = relu(y1 @ F1^T) ----
  {
    f32x4 acc[3][4] = {};
    #pragma unroll
    for (int ks = 0; ks < 2; ++ks) {
      short8 af[3];
      #pragma unroll
      for (int mi = 0; mi < 3; ++mi)
        af[mi] = *(const short8*)&Ybuf[((wm*3+mi)*16 + l15)*72 + ks*32 + l4*8];
      #pragma unroll
      for (int i = 0; i < 4; ++i) {
        int nt = wn*4 + i;
        short8 bf = *(const short8*)&F1[(size_t)(nt*16 + l15)*64 + ks*32 + l4*8];
        #pragma unroll
        for (int mi = 0; mi < 3; ++mi)
          acc[mi][i] = MFMA16(af[mi], bf, acc[mi][i]);
      }
    }
    #pragma unroll
    for (int i = 0; i < 4; ++i) {
      int col = (wn*4+i)*16 + l15;
      float bias = f1b[col];
      #pragma unroll
      for (int mi = 0; mi < 3; ++mi)
        #pragma unroll
        for (int r = 0; r < 4; ++r)
          Hb[((wm*3+mi)*16 + l4*4 + r)*280 + col] = f2bf(fmaxf(acc[mi][i][r] + bias, 0.f));
    }
  }
  __syncthreads();

  // ---- FF2 + residual + LN2 (single barrier) + store y2 bf16 ----
  {
    f32x4 acc[3] = {};
    #pragma unroll
    for (int ks = 0; ks < 8; ++ks) {
      short8 bf = *(const short8*)&F2[(size_t)(wn*16 + l15)*256 + ks*32 + l4*8];
      #pragma unroll
      for (int mi = 0; mi < 3; ++mi) {
        short8 af = *(const short8*)&Hb[((wm*3+mi)*16 + l15)*280 + ks*32 + l4*8];
        acc[mi] = MFMA16(af, bf, acc[mi]);
      }
    }
    int col = wn*16 + l15;
    float bias = f2b[col];
    #pragma unroll
    for (int mi = 0; mi < 3; ++mi)
      #pragma unroll
      for (int r = 0; r < 4; ++r) {
        int row = (wm*3+mi)*16 + l4*4 + r;
        float z = acc[mi][r] + bias + bf2f(Ybuf[row*72 + col]);
        acc[mi][r] = z;
        float s1 = z, s2 = z*z;
        #pragma unroll
        for (int off = 1; off <= 8; off <<= 1) { s1 += __shfl_xor(s1, off); s2 += __shfl_xor(s2, off); }
        if (l15 == 0) { part1[row][wn] = s1; part2[row][wn] = s2; }
      }
    __syncthreads();
    float gv = g2[col], bvv = be2[col];
    #pragma unroll
    for (int mi = 0; mi < 3; ++mi)
      #pragma unroll
      for (int r = 0; r < 4; ++r) {
        int row = (wm*3+mi)*16 + l4*4 + r;
        float4 p1 = *(const float4*)part1[row];
        float4 p2 = *(const float4*)part2[row];
        float mu  = (p1.x + p1.y + p1.z + p1.w) * (1.f/64.f);
        float var = (p2.x + p2.y + p2.z + p2.w) * (1.f/64.f) - mu*mu;
        outg[base + row*64 + col] = f2bf((acc[mi][r] - mu) * rsqrtf(var + 1e-5f) * gv + bvv);
      }
  }
}

// ---------------- K7: fuse-matrix prep ----------------
__global__ void k_mvec(const float* __restrict__ flow, const float* __restrict__ clw,
                       const float* __restrict__ clb, float* __restrict__ mv)
{
  int n = blockIdx.x*blockDim.x + threadIdx.x;
  if (n < N_) {
    float s = 0.f;
    float bias = clb[0];
    for (int b = 0; b < B_; ++b) {
      const float* f = flow + ((size_t)b*N_ + n)*T_;
      float acc = bias;
      #pragma unroll
      for (int t = 0; t < T_; ++t) acc += f[t]*clw[t];
      s += fmaxf(acc, 0.f);
    }
    mv[n] = s * (1.f/16.f);
  }
}

__global__ void k_fusemat(const float* __restrict__ mv, unsigned short* __restrict__ F)
{
  int idx = blockIdx.x*256 + threadIdx.x;
  int m = idx >> 10, n = idx & 1023;
  float x = 0.5f*(mv[m] + mv[n]);
  F[idx] = f2bf(1.f/(1.f + __expf(-x)));
}

// ---------------- launch ----------------
extern "C" void kernel_launch(void* const* d_in, const int* in_sizes, int n_in,
                              void* d_out, int out_size, void* d_ws, size_t ws_size,
                              hipStream_t stream)
{
  const float* flow = (const float*)d_in[0];
  const int*   day  = (const int*)d_in[1];
  const int*   week = (const int*)d_in[2];
  const float* semb = (const float*)d_in[3];
  const float* demb = (const float*)d_in[4];
  const float* wemb = (const float*)d_in[5];
  const float* gfsw = (const float*)d_in[6];
  const float* gfsb = (const float*)d_in[7];
  const float* gluw = (const float*)d_in[8];
  const float* glub = (const float*)d_in[9];
  const float* gcw  = (const float*)d_in[10];
  const float* gcA  = (const float*)d_in[11];
  const float* gcA2 = (const float*)d_in[12];
  const float* wi   = (const float*)d_in[13];
  const float* bi   = (const float*)d_in[14];
  const float* w1m  = (const float*)d_in[15];
  const float* b1m  = (const float*)d_in[16];
  const float* w1g  = (const float*)d_in[17];
  const float* b1g  = (const float*)d_in[18];
  const float* w2m  = (const float*)d_in[19];
  const float* b2m  = (const float*)d_in[20];
  const float* w2g  = (const float*)d_in[21];
  const float* b2g  = (const float*)d_in[22];
  const float* wfc  = (const float*)d_in[23];
  const float* bfc  = (const float*)d_in[24];
  const float* wq   = (const float*)d_in[25];
  const float* bq   = (const float*)d_in[26];
  const float* wk   = (const float*)d_in[27];
  const float* bk   = (const float*)d_in[28];
  const float* wv   = (const float*)d_in[29];
  const float* bv   = (const float*)d_in[30];
  const float* wo   = (const float*)d_in[31];
  const float* bo   = (const float*)d_in[32];
  const float* f1w  = (const float*)d_in[33];
  const float* f1b  = (const float*)d_in[34];
  const float* f2w  = (const float*)d_in[35];
  const float* f2b  = (const float*)d_in[36];
  const float* g1   = (const float*)d_in[37];
  const float* be1  = (const float*)d_in[38];
  const float* g2   = (const float*)d_in[39];
  const float* be2  = (const float*)d_in[40];
  const float* clw  = (const float*)d_in[41];
  const float* clb  = (const float*)d_in[42];

  float* out = (float*)d_out;
  char* ws = (char*)d_ws;
  unsigned short* Amat = (unsigned short*)ws;                               // 2 MB
  float* mv  = (float*)(ws + (size_t)2*1024*1024);                          // 64 KB region
  unsigned short* wTe = (unsigned short*)(ws + (size_t)2*1024*1024 + 64*1024); // 64 KB region
  unsigned short* wds = (unsigned short*)(ws + (size_t)2*1024*1024 + 128*1024); // 192 KB region
  unsigned short* wat = (unsigned short*)(ws + (size_t)2*1024*1024 + 320*1024); // 128 KB region
  unsigned short* xw  = (unsigned short*)(ws + (size_t)3*1024*1024);        // 24 MB
  unsigned short* xds = (unsigned short*)(ws + (size_t)28*1024*1024);       // 24 MB

  k_wprep_e2<<<64, 256, 0, stream>>>(gfsw, gluw, gcw, wTe);
  k_wprep3<<<96, 256, 0, stream>>>(wi, w1m, w1g, w2m, w2g, wfc, wds);
  k_wprep4<<<192, 256, 0, stream>>>(wq, wk, wv, wo, f1w, f2w, wat);
  // xw = GLU(gfs_fc(embed)) @ gc_weight -> bf16   (full MFMA)
  k_embed3<<<BNT/128, 256, 0, stream>>>(flow, day, week, semb, demb, wemb,
                                        wTe, gfsb, glub, xw);
  // combined adjacency (bf16)
  k_aprep<<<N_, 256, 0, stream>>>(gcA, gcA2, Amat);
  // xds = relu(A @ xw) -> bf16
  dim3 gg(TD/128, N_/128, B_);
  k_gemm_mfma<1,1><<<gg, 256, 0, stream>>>(Amat, xw, xds, N_, TD);
  // ds block (MFMA) -> bf16, in-place on xds
  k_ds3<<<BN_/8, 256, 0, stream>>>(xds, wds, bi, b1m, b1g, b2m, b2g, bfc, xds);
  // y2 = attn+ffn block (MFMA, 8 bn / 512 thr) -> bf16 (reuse xw region)
  k_attn4<<<BN_/8, 512, 0, stream>>>(xds, wat, bq, bk, bv, bo, f1b, f2b,
                                     g1, be1, g2, be2, xw);
  // fuse matrix (bf16, reuse Amat region)
  k_mvec<<<N_/256, 256, 0, stream>>>(flow, clw, clb, mv);
  k_fusemat<<<(N_*N_)/256, 256, 0, stream>>>(mv, Amat);
  // out = fuse @ y2 -> d_out (fp32)
  k_gemm_mfma<0,0><<<gg, 256, 0, stream>>>(Amat, xw, out, N_, TD);
}

// Round 14
// 330.364 us; speedup vs baseline: 1.0335x; 1.0335x over previous
//
#include <hip/hip_runtime.h>
#include <hip/hip_bf16.h>
#include <cstdint>

#define B_ 16
#define N_ 1024
#define T_ 12
#define HD 64
#define BN_ (B_*N_)     // 16384
#define BNT (B_*N_*T_)  // 196608
#define TD (T_*HD)      // 768

typedef __attribute__((ext_vector_type(8))) short short8;
typedef __attribute__((ext_vector_type(4))) float f32x4;

#define MFMA16(a,b,c) __builtin_amdgcn_mfma_f32_16x16x32_bf16(a,b,c,0,0,0)

__device__ __forceinline__ float sigmoidf_(float x) { return 1.f / (1.f + __expf(-x)); }

__device__ __forceinline__ unsigned short f2bf(float f) {
  __hip_bfloat16 h = __float2bfloat16(f);
  return __builtin_bit_cast(unsigned short, h);
}
__device__ __forceinline__ unsigned int f2bf2(float lo, float hi) {
  return (unsigned int)f2bf(lo) | ((unsigned int)f2bf(hi) << 16);
}
__device__ __forceinline__ float bf2f(unsigned short h) {
  unsigned int u = ((unsigned int)h) << 16;
  return __uint_as_float(u);
}

// ---------------- reductions ----------------
__device__ __forceinline__ float blkRedMax(float v, float* red) {
  #pragma unroll
  for (int off = 32; off >= 1; off >>= 1) v = fmaxf(v, __shfl_xor(v, off));
  int w = threadIdx.x >> 6;
  if ((threadIdx.x & 63) == 0) red[w] = v;
  __syncthreads();
  v = fmaxf(fmaxf(red[0], red[1]), fmaxf(red[2], red[3]));
  __syncthreads();
  return v;
}
__device__ __forceinline__ float blkRedSum(float v, float* red) {
  #pragma unroll
  for (int off = 32; off >= 1; off >>= 1) v += __shfl_xor(v, off);
  int w = threadIdx.x >> 6;
  if ((threadIdx.x & 63) == 0) red[w] = v;
  __syncthreads();
  v = red[0] + red[1] + red[2] + red[3];
  __syncthreads();
  return v;
}

// ---------------- K-wprep-all: fused weight prep (embed + ds + attn) ----------------
__global__ void k_wprep_all(
    const float* __restrict__ w1, const float* __restrict__ w2, const float* __restrict__ gcw,
    const float* __restrict__ wi,
    const float* __restrict__ w1m, const float* __restrict__ w1g,
    const float* __restrict__ w2m, const float* __restrict__ w2g,
    const float* __restrict__ wfc,
    const float* __restrict__ wq, const float* __restrict__ wk,
    const float* __restrict__ wv, const float* __restrict__ wo,
    const float* __restrict__ f1w, const float* __restrict__ f2w,
    unsigned short* __restrict__ wTe, unsigned short* __restrict__ wds,
    unsigned short* __restrict__ wat)
{
  int t = blockIdx.x*256 + threadIdx.x;   // 192*256 = 49152
  // ---- attn weights (49152 u16) ----
  if (t < 4096)        wat[t] = f2bf(wq[t]);
  else if (t < 8192)   wat[t] = f2bf(wk[t-4096]);
  else if (t < 12288)  wat[t] = f2bf(wv[t-8192]);
  else if (t < 16384)  wat[t] = f2bf(wo[t-12288]);
  else if (t < 32768)  wat[t] = f2bf(f1w[t-16384]);
  else                 wat[t] = f2bf(f2w[t-32768]);
  // ---- embed weights (16384 u16) ----
  if (t < 4096)       wTe[t] = f2bf(w1[t]);
  else if (t < 12288) wTe[t] = f2bf(w2[t-4096]);
  else if (t < 16384) {
    int r = t - 12288, e = r >> 6, d = r & 63;
    wTe[12288 + e*64 + d] = f2bf(gcw[d*64 + e]);
  }
  // ---- ds conv weights (tap-major) ----
  if (t < 24576) {
    int o = t / 192, k = t - o*192, tap = k >> 6, i = k & 63;
    wds[o*192 + k] = f2bf(wi[(o*64 + i)*3 + tap]);
  }
  if (t < 12288) {
    int o = t / 192, k = t - o*192, tap = k >> 6, i = k & 63;
    int src = (o*64 + i)*3 + tap;
    wds[24576 + o*192 + k]      = f2bf(w1m[src]);
    wds[24576 + (64+o)*192 + k] = f2bf(w1g[src]);
    wds[49152 + o*192 + k]      = f2bf(w2m[src]);
    wds[49152 + (64+o)*192 + k] = f2bf(w2g[src]);
  }
  if (t < 8192) wds[73728 + t] = f2bf(wfc[t]);
}

// ---------------- K1: embed + gfs_fc + GLU + (x @ gc_weight), full MFMA ----------------
__global__ __launch_bounds__(256) void k_embed3(
    const float* __restrict__ flow, const int* __restrict__ day, const int* __restrict__ week,
    const float* __restrict__ semb, const float* __restrict__ demb, const float* __restrict__ wemb,
    const unsigned short* __restrict__ wTe, const float* __restrict__ b1,
    const float* __restrict__ b2,
    unsigned short* __restrict__ outw)
{
  __shared__ unsigned short sEa[128*72];
  __shared__ unsigned short sEb[128*72];
  const unsigned short* W1  = wTe;
  const unsigned short* W2  = wTe + 4096;
  const unsigned short* GcT = wTe + 12288;

  int tid = threadIdx.x, lane = tid & 63, w = tid >> 6;
  int l15 = lane & 15, l4 = lane >> 4;
  int row0 = blockIdx.x * 128;

  for (int i = tid; i < 8192; i += 256) {
    int r = i >> 6, c = i & 63;
    int row = row0 + r;
    int n = (row / T_) & (N_-1);
    float val;
    if (c == 0)      val = flow[row];
    else if (c < 33) val = semb[n*32 + (c-1)];
    else if (c < 49) val = demb[day[row]*16 + (c-33)];
    else             val = wemb[week[row]*15 + (c-49)];
    sEa[r*72 + c] = f2bf(val);
  }
  __syncthreads();

  {
    f32x4 acc[8] = {};
    #pragma unroll
    for (int ks = 0; ks < 2; ++ks) {
      short8 bf = *(const short8*)&W1[(w*16 + l15)*64 + ks*32 + l4*8];
      #pragma unroll
      for (int mt = 0; mt < 8; ++mt) {
        short8 af = *(const short8*)&sEa[(mt*16 + l15)*72 + ks*32 + l4*8];
        acc[mt] = MFMA16(af, bf, acc[mt]);
      }
    }
    float bias = b1[w*16 + l15];
    #pragma unroll
    for (int mt = 0; mt < 8; ++mt)
      #pragma unroll
      for (int r = 0; r < 4; ++r)
        sEb[(mt*16 + l4*4 + r)*72 + w*16 + l15] = f2bf(acc[mt][r] + bias);
  }
  __syncthreads();

  {
    f32x4 alo[8] = {}, ahi[8] = {};
    #pragma unroll
    for (int ks = 0; ks < 2; ++ks) {
      short8 blo = *(const short8*)&W2[(size_t)(w*16 + l15)*64 + ks*32 + l4*8];
      short8 bhi = *(const short8*)&W2[(size_t)(64 + w*16 + l15)*64 + ks*32 + l4*8];
      #pragma unroll
      for (int mt = 0; mt < 8; ++mt) {
        short8 af = *(const short8*)&sEb[(mt*16 + l15)*72 + ks*32 + l4*8];
        alo[mt] = MFMA16(af, blo, alo[mt]);
        ahi[mt] = MFMA16(af, bhi, ahi[mt]);
      }
    }
    float blov = b2[w*16 + l15], bhiv = b2[64 + w*16 + l15];
    #pragma unroll
    for (int mt = 0; mt < 8; ++mt)
      #pragma unroll
      for (int r = 0; r < 4; ++r) {
        float v = (alo[mt][r] + blov) * sigmoidf_(ahi[mt][r] + bhiv);
        sEa[(mt*16 + l4*4 + r)*72 + w*16 + l15] = f2bf(v);
      }
  }
  __syncthreads();

  {
    f32x4 acc[8] = {};
    #pragma unroll
    for (int ks = 0; ks < 2; ++ks) {
      short8 bf = *(const short8*)&GcT[(w*16 + l15)*64 + ks*32 + l4*8];
      #pragma unroll
      for (int mt = 0; mt < 8; ++mt) {
        short8 af = *(const short8*)&sEa[(mt*16 + l15)*72 + ks*32 + l4*8];
        acc[mt] = MFMA16(af, bf, acc[mt]);
      }
    }
    #pragma unroll
    for (int mt = 0; mt < 8; ++mt)
      #pragma unroll
      for (int r = 0; r < 4; ++r)
        outw[(size_t)(row0 + mt*16 + l4*4 + r)*64 + w*16 + l15] = f2bf(acc[mt][r]);
  }
}

// ---------------- K2: A = softmax(relu(A1),1) + softmax(relu(A2),1), bf16 out ------------
__global__ __launch_bounds__(256) void k_aprep(
    const float* __restrict__ A1, const float* __restrict__ A2, unsigned short* __restrict__ Aout)
{
  __shared__ float red[4];
  int m = blockIdx.x, tid = threadIdx.x;
  float mx0, is0, mx1, is1;
  {
    const float* src = A1 + (size_t)m*N_;
    float mx = 0.f;
    for (int i = tid; i < N_; i += 256) mx = fmaxf(mx, fmaxf(src[i], 0.f));
    mx = blkRedMax(mx, red);
    float s = 0.f;
    for (int i = tid; i < N_; i += 256) s += __expf(fmaxf(src[i], 0.f) - mx);
    s = blkRedSum(s, red);
    mx0 = mx; is0 = 1.f / s;
  }
  {
    const float* src = A2 + (size_t)m*N_;
    float mx = 0.f;
    for (int i = tid; i < N_; i += 256) mx = fmaxf(mx, fmaxf(src[i], 0.f));
    mx = blkRedMax(mx, red);
    float s = 0.f;
    for (int i = tid; i < N_; i += 256) s += __expf(fmaxf(src[i], 0.f) - mx);
    s = blkRedSum(s, red);
    mx1 = mx; is1 = 1.f / s;
  }
  const float* s1 = A1 + (size_t)m*N_;
  const float* s2 = A2 + (size_t)m*N_;
  for (int i = tid; i < N_; i += 256) {
    float v1 = __expf(fmaxf(s1[i], 0.f) - mx0) * is0;
    float v2 = __expf(fmaxf(s2[i], 0.f) - mx1) * is1;
    Aout[(size_t)m*N_ + i] = f2bf(v1 + v2);
  }
}

// ---------------- K3: bf16 MFMA batched GEMM ----------------
template<int RELU, int OB16>
__global__ __launch_bounds__(256) void k_gemm_mfma(
    const unsigned short* __restrict__ A, const unsigned short* __restrict__ X,
    void* __restrict__ C, int K, int P)
{
  __shared__ unsigned short sA[128*40];
  __shared__ unsigned short sB[128*40];
  int tid = threadIdx.x, lane = tid & 63, wid = tid >> 6;
  int M = gridDim.y * 128;
  int b = blockIdx.z;
  const unsigned short* Xb = X + (size_t)b*K*P;
  int m0 = blockIdx.y*128, p0 = blockIdx.x*128;
  int wr = wid >> 1, wc = wid & 1;

  f32x4 acc[4][4] = {};

  for (int k0 = 0; k0 < K; k0 += 32) {
    #pragma unroll
    for (int pass = 0; pass < 2; ++pass) {
      int r = (tid >> 2) + 64*pass, kk = (tid & 3)*8;
      short8 v = *(const short8*)&A[(size_t)(m0+r)*K + k0 + kk];
      *(short8*)&sA[r*40 + kk] = v;
    }
    #pragma unroll
    for (int pass = 0; pass < 4; ++pass) {
      int p  = (tid & 63) + 64*(pass & 1);
      int k4 = (tid >> 6)*4 + 16*(pass >> 1);
      ushort4 h;
      h.x = Xb[(size_t)(k0+k4+0)*P + p0 + p];
      h.y = Xb[(size_t)(k0+k4+1)*P + p0 + p];
      h.z = Xb[(size_t)(k0+k4+2)*P + p0 + p];
      h.w = Xb[(size_t)(k0+k4+3)*P + p0 + p];
      *(ushort4*)&sB[p*40 + k4] = h;
    }
    __syncthreads();
    short8 af[4], bf[4];
    #pragma unroll
    for (int f = 0; f < 4; ++f) {
      af[f] = *(const short8*)&sA[(wr*64 + f*16 + (lane & 15))*40 + (lane >> 4)*8];
      bf[f] = *(const short8*)&sB[(wc*64 + f*16 + (lane & 15))*40 + (lane >> 4)*8];
    }
    #pragma unroll
    for (int fm = 0; fm < 4; ++fm)
      #pragma unroll
      for (int fn = 0; fn < 4; ++fn)
        acc[fm][fn] = MFMA16(af[fm], bf[fn], acc[fm][fn]);
    __syncthreads();
  }
  #pragma unroll
  for (int fm = 0; fm < 4; ++fm) {
    int row = m0 + wr*64 + fm*16 + (lane >> 4)*4;
    #pragma unroll
    for (int fn = 0; fn < 4; ++fn) {
      int col = p0 + wc*64 + fn*16 + (lane & 15);
      #pragma unroll
      for (int r = 0; r < 4; ++r) {
        float v = acc[fm][fn][r];
        if (RELU) v = fmaxf(v, 0.f);
        if (OB16) {
          unsigned short* Cb = (unsigned short*)C + (size_t)b*M*P;
          Cb[(size_t)(row + r)*P + col] = f2bf(v);
        } else {
          float* Cb = (float*)C + (size_t)b*M*P;
          Cb[(size_t)(row + r)*P + col] = v;
        }
      }
    }
  }
}

// ---------------- K5: ds temporal-conv block, MFMA, 8 bn per block; bf16 out (in-place) ----
__global__ __launch_bounds__(256) void k_ds3(
    const unsigned short* xds,
    const unsigned short* __restrict__ Wall,
    const float* __restrict__ bi,
    const float* __restrict__ b1m, const float* __restrict__ b1g,
    const float* __restrict__ b2m, const float* __restrict__ b2g,
    const float* __restrict__ bfc,
    unsigned short* outg)
{
  __shared__ unsigned short smem[36352];
  unsigned short* X_lds  = smem;               // [8][14][72]
  unsigned short* xi_lds = smem + 8064;        // [8][14][136]
  unsigned short* fu_lds = smem + 23296;       // [96][136]
  const unsigned short* WiB  = Wall;
  const unsigned short* Wg1B = Wall + 24576;
  const unsigned short* Wg2B = Wall + 49152;
  const unsigned short* WfB  = Wall + 73728;

  int tid = threadIdx.x, lane = tid & 63, wid = tid >> 6;
  int l15 = lane & 15, l4 = lane >> 4;
  int bn0 = blockIdx.x * 8;

  for (int i = tid; i < 8*2*72; i += 256) {
    int g = i / 144, r = i - g*144;
    int tp = (r < 72) ? 0 : 13, c = (r < 72) ? r : r - 72;
    X_lds[(g*14 + tp)*72 + c] = 0;
  }
  for (int i = tid; i < 8*2*136; i += 256) {
    int g = i / 272, r = i - g*272;
    int tp = (r < 136) ? 0 : 13, c = (r < 136) ? r : r - 136;
    xi_lds[(g*14 + tp)*136 + c] = 0;
  }
  for (int i = tid; i < 768; i += 256) {
    int g = i / 96, rem = i - g*96, t = rem >> 3, i8 = rem & 7;
    short8 v = *(const short8*)&xds[(size_t)(bn0+g)*768 + t*64 + i8*8];
    *(short8*)&X_lds[(g*14 + t + 1)*72 + i8*8] = v;
  }
  __syncthreads();

  int ga[6], ta[6];
  #pragma unroll
  for (int mt = 0; mt < 6; ++mt) {
    int r = mt*16 + l15;
    ga[mt] = r / 12; ta[mt] = r - ga[mt]*12;
  }

  {
    f32x4 acc1[6][2] = {};
    int nb = wid*2;
    #pragma unroll
    for (int ks = 0; ks < 6; ++ks) {
      int tap = ks >> 1, i0 = (ks & 1)*32;
      short8 af[6];
      #pragma unroll
      for (int mt = 0; mt < 6; ++mt)
        af[mt] = *(const short8*)&X_lds[(ga[mt]*14 + ta[mt] + tap)*72 + i0 + l4*8];
      short8 bf0 = *(const short8*)&WiB[(size_t)((nb  )*16 + l15)*192 + ks*32 + l4*8];
      short8 bf1 = *(const short8*)&WiB[(size_t)((nb+1)*16 + l15)*192 + ks*32 + l4*8];
      #pragma unroll
      for (int mt = 0; mt < 6; ++mt) {
        acc1[mt][0] = MFMA16(af[mt], bf0, acc1[mt][0]);
        acc1[mt][1] = MFMA16(af[mt], bf1, acc1[mt][1]);
      }
    }
    #pragma unroll
    for (int nn = 0; nn < 2; ++nn) {
      int o = (nb+nn)*16 + l15;
      float bv = bi[o];
      #pragma unroll
      for (int mt = 0; mt < 6; ++mt) {
        #pragma unroll
        for (int reg = 0; reg < 4; ++reg) {
          int r = mt*16 + l4*4 + reg;
          int g = r / 12, t = r - g*12;
          xi_lds[(g*14 + t + 1)*136 + o] = f2bf(acc1[mt][nn][reg] + bv);
        }
      }
    }
  }
  __syncthreads();

  #pragma unroll
  for (int h = 0; h < 2; ++h) {
    const unsigned short* Wg = h ? Wg2B : Wg1B;
    f32x4 am[6] = {}, ag[6] = {};
    #pragma unroll
    for (int ks = 0; ks < 6; ++ks) {
      int tap = ks >> 1, i0 = (ks & 1)*32;
      short8 af[6];
      #pragma unroll
      for (int mt = 0; mt < 6; ++mt)
        af[mt] = *(const short8*)&xi_lds[(ga[mt]*14 + ta[mt] + tap)*136 + h*64 + i0 + l4*8];
      short8 bm = *(const short8*)&Wg[(size_t)(wid*16 + l15)*192 + ks*32 + l4*8];
      short8 bg = *(const short8*)&Wg[(size_t)((wid+4)*16 + l15)*192 + ks*32 + l4*8];
      #pragma unroll
      for (int mt = 0; mt < 6; ++mt) {
        am[mt] = MFMA16(af[mt], bm, am[mt]);
        ag[mt] = MFMA16(af[mt], bg, ag[mt]);
      }
    }
    int o = wid*16 + l15;
    float bmv = (h ? b2m : b1m)[o];
    float bgv = (h ? b2g : b1g)[o];
    #pragma unroll
    for (int mt = 0; mt < 6; ++mt) {
      #pragma unroll
      for (int reg = 0; reg < 4; ++reg) {
        int r = mt*16 + l4*4 + reg;
        int g = r / 12, t = r - g*12;
        float pm = am[mt][reg] + bmv;
        float pg = ag[mt][reg] + bgv;
        float po = pm * sigmoidf_(pg);
        float xi = bf2f(xi_lds[(g*14 + t + 1)*136 + h*64 + o]);
        fu_lds[r*136 + h*64 + o] = f2bf(fmaxf(po + xi, 0.f));
      }
    }
  }
  __syncthreads();

  {
    f32x4 a3[6] = {};
    #pragma unroll
    for (int ks = 0; ks < 4; ++ks) {
      short8 af = *(const short8*)&WfB[(size_t)(wid*16 + l15)*128 + ks*32 + l4*8];
      #pragma unroll
      for (int nt = 0; nt < 6; ++nt) {
        short8 bf = *(const short8*)&fu_lds[(nt*16 + l15)*136 + ks*32 + l4*8];
        a3[nt] = MFMA16(af, bf, a3[nt]);
      }
    }
    int e0 = wid*16 + l4*4;
    float4 bb = *(const float4*)&bfc[e0];
    #pragma unroll
    for (int nt = 0; nt < 6; ++nt) {
      uint2 vv;
      vv.x = f2bf2(a3[nt][0] + bb.x, a3[nt][1] + bb.y);
      vv.y = f2bf2(a3[nt][2] + bb.z, a3[nt][3] + bb.w);
      *(uint2*)&outg[((size_t)(bn0 + ga[nt])*12 + ta[nt])*64 + e0] = vv;
    }
  }
}

// ---------------- K6: attention + FFN + 2x LN, full MFMA, 8 bn / 512 thr per block ------
// R11 structure + PREFETCHED operand fragments (loads batched before MFMA chains).
__global__ __launch_bounds__(512) void k_attn4(
    const unsigned short* __restrict__ xg,     // bf16 [BN][12][64]
    const unsigned short* __restrict__ Wat,
    const float* __restrict__ bq, const float* __restrict__ bk, const float* __restrict__ bv,
    const float* __restrict__ bo,
    const float* __restrict__ f1b, const float* __restrict__ f2b,
    const float* __restrict__ g1, const float* __restrict__ be1,
    const float* __restrict__ g2, const float* __restrict__ be2,
    unsigned short* __restrict__ outg)
{
  __shared__ unsigned short su[36864];
  __shared__ float part[2][4][96];
  __shared__ float stats[2][96];
  unsigned short* Ybuf = su;            // [96][72]
  unsigned short* Qkv  = su + 6912;     // [96][216]
  unsigned short* Hb   = su + 6912;     // [96][280] (union with Qkv)
  unsigned short* atts = su + 33792;    // [8][16][24]

  const unsigned short* Wqkv = Wat;
  const unsigned short* Wo   = Wat + 12288;
  const unsigned short* F1   = Wat + 16384;
  const unsigned short* F2   = Wat + 32768;

  int tid = threadIdx.x, lane = tid & 63, w = tid >> 6;
  int l15 = lane & 15, l4 = lane >> 4;
  int wn = w & 3, wm = w >> 2;
  size_t base = (size_t)blockIdx.x * 8 * 768;

  for (int i = tid; i < 768; i += 512) {
    int r = i >> 3, c = i & 7;
    *(short8*)&Ybuf[r*72 + c*8] = *(const short8*)&xg[base + r*64 + c*8];
  }
  __syncthreads();

  // ---- QKV GEMM: Qkv[96][192] — prefetch 12 frags, then 18 MFMA ----
  {
    short8 afA[2][3], bfA[2][3];
    #pragma unroll
    for (int ks = 0; ks < 2; ++ks) {
      #pragma unroll
      for (int ni = 0; ni < 3; ++ni)
        bfA[ks][ni] = *(const short8*)&Wqkv[(size_t)((wn*3+ni)*16 + l15)*64 + ks*32 + l4*8];
      #pragma unroll
      for (int mi = 0; mi < 3; ++mi)
        afA[ks][mi] = *(const short8*)&Ybuf[((wm*3+mi)*16 + l15)*72 + ks*32 + l4*8];
    }
    f32x4 acc[3][3] = {};
    #pragma unroll
    for (int ks = 0; ks < 2; ++ks)
      #pragma unroll
      for (int ni = 0; ni < 3; ++ni)
        #pragma unroll
        for (int mi = 0; mi < 3; ++mi)
          acc[mi][ni] = MFMA16(afA[ks][mi], bfA[ks][ni], acc[mi][ni]);
    #pragma unroll
    for (int ni = 0; ni < 3; ++ni) {
      int col = (wn*3+ni)*16 + l15;
      float bias = col < 64 ? bq[col] : (col < 128 ? bk[col-64] : bv[col-128]);
      #pragma unroll
      for (int mi = 0; mi < 3; ++mi)
        #pragma unroll
        for (int r = 0; r < 4; ++r)
          Qkv[((wm*3+mi)*16 + l4*4 + r)*216 + col] = f2bf(acc[mi][ni][r] + bias);
    }
  }
  __syncthreads();

  // ---- attention: wave w owns bn w; o -> Qkv q-region ----
  {
    int rb = w*12;
    unsigned short* as = atts + w*384;   // [16][24]
    #pragma unroll
    for (int h = 0; h < 4; ++h) {
      short8 kf = {}, qf = {};
      if (l4 < 2) {
        kf = *(const short8*)&Qkv[(rb + l15)*216 + 64 + h*16 + l4*8];
        qf = *(const short8*)&Qkv[(rb + l15)*216 +      h*16 + l4*8];
      }
      f32x4 sc = {};
      sc = MFMA16(kf, qf, sc);
      float e[4]; float mx = -3e38f;
      #pragma unroll
      for (int r = 0; r < 4; ++r) {
        float v = (l4 == 3) ? -3e38f : sc[r]*0.25f;
        e[r] = v; mx = fmaxf(mx, v);
      }
      mx = fmaxf(mx, __shfl_xor(mx, 16));
      mx = fmaxf(mx, __shfl_xor(mx, 32));
      float s = 0.f;
      #pragma unroll
      for (int r = 0; r < 4; ++r) { e[r] = __expf(e[r] - mx); s += e[r]; }
      s += __shfl_xor(s, 16); s += __shfl_xor(s, 32);
      float inv = 1.f/s;
      uint2 pk = make_uint2(f2bf2(e[0]*inv, e[1]*inv), f2bf2(e[2]*inv, e[3]*inv));
      *(uint2*)&as[l15*24 + l4*4] = pk;
      short8 aaf = {};
      if (l4 < 2) aaf = *(const short8*)&as[l15*24 + l4*8];
      short8 vf = {};
      if (l4 < 2) {
        #pragma unroll
        for (int j = 0; j < 8; ++j) {
          int s_ = l4*8 + j;
          vf[j] = (s_ < 12) ? (short)Qkv[(rb + s_)*216 + 128 + h*16 + l15] : (short)0;
        }
      }
      f32x4 o = {};
      o = MFMA16(aaf, vf, o);
      if (l4 < 3) {
        #pragma unroll
        for (int r = 0; r < 4; ++r)
          Qkv[(rb + l4*4 + r)*216 + h*16 + l15] = f2bf(o[r]);   // q-region (dead)
      }
    }
  }
  __syncthreads();

  // ---- WO GEMM (prefetch 8 frags) + residual(LDS) + LN1 ----
  {
    short8 bfA[2], afA[2][3];
    #pragma unroll
    for (int ks = 0; ks < 2; ++ks) {
      bfA[ks] = *(const short8*)&Wo[(size_t)(wn*16 + l15)*64 + ks*32 + l4*8];
      #pragma unroll
      for (int mi = 0; mi < 3; ++mi)
        afA[ks][mi] = *(const short8*)&Qkv[((wm*3+mi)*16 + l15)*216 + ks*32 + l4*8];
    }
    f32x4 zacc[3] = {};
    #pragma unroll
    for (int ks = 0; ks < 2; ++ks)
      #pragma unroll
      for (int mi = 0; mi < 3; ++mi)
        zacc[mi] = MFMA16(afA[ks][mi], bfA[ks], zacc[mi]);
    int col = wn*16 + l15;
    float bias = bo[col];
    #pragma unroll
    for (int mi = 0; mi < 3; ++mi)
      #pragma unroll
      for (int r = 0; r < 4; ++r) {
        int row = (wm*3+mi)*16 + l4*4 + r;
        float z = zacc[mi][r] + bias + bf2f(Ybuf[row*72 + col]);
        zacc[mi][r] = z;
        float s1 = z, s2 = z*z;
        #pragma unroll
        for (int off = 1; off <= 8; off <<= 1) { s1 += __shfl_xor(s1, off); s2 += __shfl_xor(s2, off); }
        if (l15 == 0) { part[0][wn][row] = s1; part[1][wn][row] = s2; }
      }
    __syncthreads();
    if (tid < 96) {
      float s = part[0][0][tid]+part[0][1][tid]+part[0][2][tid]+part[0][3][tid];
      float q = part[1][0][tid]+part[1][1][tid]+part[1][2][tid]+part[1][3][tid];
      float mu = s * (1.f/64.f);
      float var = q * (1.f/64.f) - mu*mu;
      stats[0][tid] = mu; stats[1][tid] = rsqrtf(var + 1e-5f);
    }
    __syncthreads();
    float gv = g1[col], bvv = be1[col];
    #pragma unroll
    for (int mi = 0; mi < 3; ++mi)
      #pragma unroll
      for (int r = 0; r < 4; ++r) {
        int row = (wm*3+mi)*16 + l4*4 + r;
        Ybuf[row*72 + col] = f2bf((zacc[mi][r] - stats[0][row]) * stats[1][row] * gv + bvv);
      }
  }
  __syncthreads();

  // ---- FF1 (prefetch 14 frags): Hb[96][256] = relu(y1 @ F1^T) ----
  {
    short8 afA[2][3], bfA[2][4];
    #pragma unroll
    for (int ks = 0; ks < 2; ++ks) {
      #pragma unroll
      for (int i = 0; i < 4; ++i)
        bfA[ks][i] = *(const short8*)&F1[(size_t)((wn*4+i)*16 + l15)*64 + ks*32 + l4*8];
      #pragma unroll
      for (int mi = 0; mi < 3; ++mi)
        afA[ks][mi] = *(const short8*)&Ybuf[((wm*3+mi)*16 + l15)*72 + ks*32 + l4*8];
    }
    f32x4 acc[3][4] = {};
    #pragma unroll
    for (int ks = 0; ks < 2; ++ks)
      #pragma unroll
      for (int i = 0; i < 4; ++i)
        #pragma unroll
        for (int mi = 0; mi < 3; ++mi)
          acc[mi][i] = MFMA16(afA[ks][mi], bfA[ks][i], acc[mi][i]);
    #pragma unroll
    for (int i = 0; i < 4; ++i) {
      int col = (wn*4+i)*16 + l15;
      float bias = f1b[col];
      #pragma unroll
      for (int mi = 0; mi < 3; ++mi)
        #pragma unroll
        for (int r = 0; r < 4; ++r)
          Hb[((wm*3+mi)*16 + l4*4 + r)*280 + col] = f2bf(fmaxf(acc[mi][i][r] + bias, 0.f));
    }
  }
  __syncthreads();

  // ---- FF2 (2 half-K chunks, 16 prefetched frags each) + residual + LN2 + store ----
  {
    f32x4 acc[3] = {};
    #pragma unroll
    for (int half = 0; half < 2; ++half) {
      short8 bfA[4], afA[4][3];
      #pragma unroll
      for (int k2 = 0; k2 < 4; ++k2) {
        int ks = half*4 + k2;
        bfA[k2] = *(const short8*)&F2[(size_t)(wn*16 + l15)*256 + ks*32 + l4*8];
        #pragma unroll
        for (int mi = 0; mi < 3; ++mi)
          afA[k2][mi] = *(const short8*)&Hb[((wm*3+mi)*16 + l15)*280 + ks*32 + l4*8];
      }
      #pragma unroll
      for (int k2 = 0; k2 < 4; ++k2)
        #pragma unroll
        for (int mi = 0; mi < 3; ++mi)
          acc[mi] = MFMA16(afA[k2][mi], bfA[k2], acc[mi]);
    }
    int col = wn*16 + l15;
    float bias = f2b[col];
    #pragma unroll
    for (int mi = 0; mi < 3; ++mi)
      #pragma unroll
      for (int r = 0; r < 4; ++r) {
        int row = (wm*3+mi)*16 + l4*4 + r;
        float z = acc[mi][r] + bias + bf2f(Ybuf[row*72 + col]);
        acc[mi][r] = z;
        float s1 = z, s2 = z*z;
        #pragma unroll
        for (int off = 1; off <= 8; off <<= 1) { s1 += __shfl_xor(s1, off); s2 += __shfl_xor(s2, off); }
        if (l15 == 0) { part[0][wn][row] = s1; part[1][wn][row] = s2; }
      }
    __syncthreads();
    if (tid < 96) {
      float s = part[0][0][tid]+part[0][1][tid]+part[0][2][tid]+part[0][3][tid];
      float q = part[1][0][tid]+part[1][1][tid]+part[1][2][tid]+part[1][3][tid];
      float mu = s * (1.f/64.f);
      float var = q * (1.f/64.f) - mu*mu;
      stats[0][tid] = mu; stats[1][tid] = rsqrtf(var + 1e-5f);
    }
    __syncthreads();
    float gv = g2[col], bvv = be2[col];
    #pragma unroll
    for (int mi = 0; mi < 3; ++mi)
      #pragma unroll
      for (int r = 0; r < 4; ++r) {
        int row = (wm*3+mi)*16 + l4*4 + r;
        outg[base + row*64 + col] = f2bf((acc[mi][r] - stats[0][row]) * stats[1][row] * gv + bvv);
      }
  }
}

// ---------------- K7: fuse-matrix prep ----------------
__global__ void k_mvec(const float* __restrict__ flow, const float* __restrict__ clw,
                       const float* __restrict__ clb, float* __restrict__ mv)
{
  int n = blockIdx.x*blockDim.x + threadIdx.x;
  if (n < N_) {
    float s = 0.f;
    float bias = clb[0];
    for (int b = 0; b < B_; ++b) {
      const float* f = flow + ((size_t)b*N_ + n)*T_;
      float acc = bias;
      #pragma unroll
      for (int t = 0; t < T_; ++t) acc += f[t]*clw[t];
      s += fmaxf(acc, 0.f);
    }
    mv[n] = s * (1.f/16.f);
  }
}

__global__ void k_fusemat(const float* __restrict__ mv, unsigned short* __restrict__ F)
{
  int idx = blockIdx.x*256 + threadIdx.x;
  int m = idx >> 10, n = idx & 1023;
  float x = 0.5f*(mv[m] + mv[n]);
  F[idx] = f2bf(1.f/(1.f + __expf(-x)));
}

// ---------------- launch ----------------
extern "C" void kernel_launch(void* const* d_in, const int* in_sizes, int n_in,
                              void* d_out, int out_size, void* d_ws, size_t ws_size,
                              hipStream_t stream)
{
  const float* flow = (const float*)d_in[0];
  const int*   day  = (const int*)d_in[1];
  const int*   week = (const int*)d_in[2];
  const float* semb = (const float*)d_in[3];
  const float* demb = (const float*)d_in[4];
  const float* wemb = (const float*)d_in[5];
  const float* gfsw = (const float*)d_in[6];
  const float* gfsb = (const float*)d_in[7];
  const float* gluw = (const float*)d_in[8];
  const float* glub = (const float*)d_in[9];
  const float* gcw  = (const float*)d_in[10];
  const float* gcA  = (const float*)d_in[11];
  const float* gcA2 = (const float*)d_in[12];
  const float* wi   = (const float*)d_in[13];
  const float* bi   = (const float*)d_in[14];
  const float* w1m  = (const float*)d_in[15];
  const float* b1m  = (const float*)d_in[16];
  const float* w1g  = (const float*)d_in[17];
  const float* b1g  = (const float*)d_in[18];
  const float* w2m  = (const float*)d_in[19];
  const float* b2m  = (const float*)d_in[20];
  const float* w2g  = (const float*)d_in[21];
  const float* b2g  = (const float*)d_in[22];
  const float* wfc  = (const float*)d_in[23];
  const float* bfc  = (const float*)d_in[24];
  const float* wq   = (const float*)d_in[25];
  const float* bq   = (const float*)d_in[26];
  const float* wk   = (const float*)d_in[27];
  const float* bk   = (const float*)d_in[28];
  const float* wv   = (const float*)d_in[29];
  const float* bv   = (const float*)d_in[30];
  const float* wo   = (const float*)d_in[31];
  const float* bo   = (const float*)d_in[32];
  const float* f1w  = (const float*)d_in[33];
  const float* f1b  = (const float*)d_in[34];
  const float* f2w  = (const float*)d_in[35];
  const float* f2b  = (const float*)d_in[36];
  const float* g1   = (const float*)d_in[37];
  const float* be1  = (const float*)d_in[38];
  const float* g2   = (const float*)d_in[39];
  const float* be2  = (const float*)d_in[40];
  const float* clw  = (const float*)d_in[41];
  const float* clb  = (const float*)d_in[42];

  float* out = (float*)d_out;
  char* ws = (char*)d_ws;
  unsigned short* Amat = (unsigned short*)ws;                               // 2 MB
  float* mv  = (float*)(ws + (size_t)2*1024*1024);                          // 64 KB region
  unsigned short* wTe = (unsigned short*)(ws + (size_t)2*1024*1024 + 64*1024); // 64 KB region
  unsigned short* wds = (unsigned short*)(ws + (size_t)2*1024*1024 + 128*1024); // 192 KB region
  unsigned short* wat = (unsigned short*)(ws + (size_t)2*1024*1024 + 320*1024); // 128 KB region
  unsigned short* xw  = (unsigned short*)(ws + (size_t)3*1024*1024);        // 24 MB
  unsigned short* xds = (unsigned short*)(ws + (size_t)28*1024*1024);       // 24 MB

  k_wprep_all<<<192, 256, 0, stream>>>(gfsw, gluw, gcw,
                                       wi, w1m, w1g, w2m, w2g, wfc,
                                       wq, wk, wv, wo, f1w, f2w,
                                       wTe, wds, wat);
  // xw = GLU(gfs_fc(embed)) @ gc_weight -> bf16   (full MFMA)
  k_embed3<<<BNT/128, 256, 0, stream>>>(flow, day, week, semb, demb, wemb,
                                        wTe, gfsb, glub, xw);
  // combined adjacency (bf16)
  k_aprep<<<N_, 256, 0, stream>>>(gcA, gcA2, Amat);
  // xds = relu(A @ xw) -> bf16
  dim3 gg(TD/128, N_/128, B_);
  k_gemm_mfma<1,1><<<gg, 256, 0, stream>>>(Amat, xw, xds, N_, TD);
  // ds block (MFMA) -> bf16, in-place on xds
  k_ds3<<<BN_/8, 256, 0, stream>>>(xds, wds, bi, b1m, b1g, b2m, b2g, bfc, xds);
  // y2 = attn+ffn block (MFMA, 8 bn / 512 thr) -> bf16 (reuse xw region)
  k_attn4<<<BN_/8, 512, 0, stream>>>(xds, wat, bq, bk, bv, bo, f1b, f2b,
                                     g1, be1, g2, be2, xw);
  // fuse matrix (bf16, reuse Amat region)
  k_mvec<<<N_/256, 256, 0, stream>>>(flow, clw, clb, mv);
  k_fusemat<<<(N_*N_)/256, 256, 0, stream>>>(mv, Amat);
  // out = fuse @ y2 -> d_out (fp32)
  k_gemm_mfma<0,0><<<gg, 256, 0, stream>>>(Amat, xw, out, N_, TD);
}

// Round 15
// 329.577 us; speedup vs baseline: 1.0360x; 1.0024x over previous
//
#include <hip/hip_runtime.h>
#include <hip/hip_bf16.h>
#include <cstdint>

#define B_ 16
#define N_ 1024
#define T_ 12
#define HD 64
#define BN_ (B_*N_)     // 16384
#define BNT (B_*N_*T_)  // 196608
#define TD (T_*HD)      // 768

typedef __attribute__((ext_vector_type(8))) short short8;
typedef __attribute__((ext_vector_type(4))) float f32x4;

#define MFMA16(a,b,c) __builtin_amdgcn_mfma_f32_16x16x32_bf16(a,b,c,0,0,0)

__device__ __forceinline__ float sigmoidf_(float x) { return 1.f / (1.f + __expf(-x)); }

__device__ __forceinline__ unsigned short f2bf(float f) {
  __hip_bfloat16 h = __float2bfloat16(f);
  return __builtin_bit_cast(unsigned short, h);
}
__device__ __forceinline__ unsigned int f2bf2(float lo, float hi) {
  return (unsigned int)f2bf(lo) | ((unsigned int)f2bf(hi) << 16);
}
__device__ __forceinline__ float bf2f(unsigned short h) {
  unsigned int u = ((unsigned int)h) << 16;
  return __uint_as_float(u);
}

// ---------------- reductions ----------------
__device__ __forceinline__ float blkRedMax(float v, float* red) {
  #pragma unroll
  for (int off = 32; off >= 1; off >>= 1) v = fmaxf(v, __shfl_xor(v, off));
  int w = threadIdx.x >> 6;
  if ((threadIdx.x & 63) == 0) red[w] = v;
  __syncthreads();
  v = fmaxf(fmaxf(red[0], red[1]), fmaxf(red[2], red[3]));
  __syncthreads();
  return v;
}
__device__ __forceinline__ float blkRedSum(float v, float* red) {
  #pragma unroll
  for (int off = 32; off >= 1; off >>= 1) v += __shfl_xor(v, off);
  int w = threadIdx.x >> 6;
  if ((threadIdx.x & 63) == 0) red[w] = v;
  __syncthreads();
  v = red[0] + red[1] + red[2] + red[3];
  __syncthreads();
  return v;
}

// ---------------- K-wprep-all: fused weight prep (embed + ds + attn) ----------------
__global__ void k_wprep_all(
    const float* __restrict__ w1, const float* __restrict__ w2, const float* __restrict__ gcw,
    const float* __restrict__ wi,
    const float* __restrict__ w1m, const float* __restrict__ w1g,
    const float* __restrict__ w2m, const float* __restrict__ w2g,
    const float* __restrict__ wfc,
    const float* __restrict__ wq, const float* __restrict__ wk,
    const float* __restrict__ wv, const float* __restrict__ wo,
    const float* __restrict__ f1w, const float* __restrict__ f2w,
    unsigned short* __restrict__ wTe, unsigned short* __restrict__ wds,
    unsigned short* __restrict__ wat)
{
  int t = blockIdx.x*256 + threadIdx.x;   // 192*256 = 49152
  if (t < 4096)        wat[t] = f2bf(wq[t]);
  else if (t < 8192)   wat[t] = f2bf(wk[t-4096]);
  else if (t < 12288)  wat[t] = f2bf(wv[t-8192]);
  else if (t < 16384)  wat[t] = f2bf(wo[t-12288]);
  else if (t < 32768)  wat[t] = f2bf(f1w[t-16384]);
  else                 wat[t] = f2bf(f2w[t-32768]);
  if (t < 4096)       wTe[t] = f2bf(w1[t]);
  else if (t < 12288) wTe[t] = f2bf(w2[t-4096]);
  else if (t < 16384) {
    int r = t - 12288, e = r >> 6, d = r & 63;
    wTe[12288 + e*64 + d] = f2bf(gcw[d*64 + e]);
  }
  if (t < 24576) {
    int o = t / 192, k = t - o*192, tap = k >> 6, i = k & 63;
    wds[o*192 + k] = f2bf(wi[(o*64 + i)*3 + tap]);
  }
  if (t < 12288) {
    int o = t / 192, k = t - o*192, tap = k >> 6, i = k & 63;
    int src = (o*64 + i)*3 + tap;
    wds[24576 + o*192 + k]      = f2bf(w1m[src]);
    wds[24576 + (64+o)*192 + k] = f2bf(w1g[src]);
    wds[49152 + o*192 + k]      = f2bf(w2m[src]);
    wds[49152 + (64+o)*192 + k] = f2bf(w2g[src]);
  }
  if (t < 8192) wds[73728 + t] = f2bf(wfc[t]);
}

// ---------------- K1: embed + gfs_fc + GLU + (x @ gc_weight), full MFMA ----------------
__global__ __launch_bounds__(256) void k_embed3(
    const float* __restrict__ flow, const int* __restrict__ day, const int* __restrict__ week,
    const float* __restrict__ semb, const float* __restrict__ demb, const float* __restrict__ wemb,
    const unsigned short* __restrict__ wTe, const float* __restrict__ b1,
    const float* __restrict__ b2,
    unsigned short* __restrict__ outw)
{
  __shared__ unsigned short sEa[128*72];
  __shared__ unsigned short sEb[128*72];
  const unsigned short* W1  = wTe;
  const unsigned short* W2  = wTe + 4096;
  const unsigned short* GcT = wTe + 12288;

  int tid = threadIdx.x, lane = tid & 63, w = tid >> 6;
  int l15 = lane & 15, l4 = lane >> 4;
  int row0 = blockIdx.x * 128;

  for (int i = tid; i < 8192; i += 256) {
    int r = i >> 6, c = i & 63;
    int row = row0 + r;
    int n = (row / T_) & (N_-1);
    float val;
    if (c == 0)      val = flow[row];
    else if (c < 33) val = semb[n*32 + (c-1)];
    else if (c < 49) val = demb[day[row]*16 + (c-33)];
    else             val = wemb[week[row]*15 + (c-49)];
    sEa[r*72 + c] = f2bf(val);
  }
  __syncthreads();

  {
    f32x4 acc[8] = {};
    #pragma unroll
    for (int ks = 0; ks < 2; ++ks) {
      short8 bf = *(const short8*)&W1[(w*16 + l15)*64 + ks*32 + l4*8];
      #pragma unroll
      for (int mt = 0; mt < 8; ++mt) {
        short8 af = *(const short8*)&sEa[(mt*16 + l15)*72 + ks*32 + l4*8];
        acc[mt] = MFMA16(af, bf, acc[mt]);
      }
    }
    float bias = b1[w*16 + l15];
    #pragma unroll
    for (int mt = 0; mt < 8; ++mt)
      #pragma unroll
      for (int r = 0; r < 4; ++r)
        sEb[(mt*16 + l4*4 + r)*72 + w*16 + l15] = f2bf(acc[mt][r] + bias);
  }
  __syncthreads();

  {
    f32x4 alo[8] = {}, ahi[8] = {};
    #pragma unroll
    for (int ks = 0; ks < 2; ++ks) {
      short8 blo = *(const short8*)&W2[(size_t)(w*16 + l15)*64 + ks*32 + l4*8];
      short8 bhi = *(const short8*)&W2[(size_t)(64 + w*16 + l15)*64 + ks*32 + l4*8];
      #pragma unroll
      for (int mt = 0; mt < 8; ++mt) {
        short8 af = *(const short8*)&sEb[(mt*16 + l15)*72 + ks*32 + l4*8];
        alo[mt] = MFMA16(af, blo, alo[mt]);
        ahi[mt] = MFMA16(af, bhi, ahi[mt]);
      }
    }
    float blov = b2[w*16 + l15], bhiv = b2[64 + w*16 + l15];
    #pragma unroll
    for (int mt = 0; mt < 8; ++mt)
      #pragma unroll
      for (int r = 0; r < 4; ++r) {
        float v = (alo[mt][r] + blov) * sigmoidf_(ahi[mt][r] + bhiv);
        sEa[(mt*16 + l4*4 + r)*72 + w*16 + l15] = f2bf(v);
      }
  }
  __syncthreads();

  {
    f32x4 acc[8] = {};
    #pragma unroll
    for (int ks = 0; ks < 2; ++ks) {
      short8 bf = *(const short8*)&GcT[(w*16 + l15)*64 + ks*32 + l4*8];
      #pragma unroll
      for (int mt = 0; mt < 8; ++mt) {
        short8 af = *(const short8*)&sEa[(mt*16 + l15)*72 + ks*32 + l4*8];
        acc[mt] = MFMA16(af, bf, acc[mt]);
      }
    }
    #pragma unroll
    for (int mt = 0; mt < 8; ++mt)
      #pragma unroll
      for (int r = 0; r < 4; ++r)
        outw[(size_t)(row0 + mt*16 + l4*4 + r)*64 + w*16 + l15] = f2bf(acc[mt][r]);
  }
}

// ---------------- K2: A = softmax(relu(A1),1) + softmax(relu(A2),1), bf16 out ------------
__global__ __launch_bounds__(256) void k_aprep(
    const float* __restrict__ A1, const float* __restrict__ A2, unsigned short* __restrict__ Aout)
{
  __shared__ float red[4];
  int m = blockIdx.x, tid = threadIdx.x;
  float mx0, is0, mx1, is1;
  {
    const float* src = A1 + (size_t)m*N_;
    float mx = 0.f;
    for (int i = tid; i < N_; i += 256) mx = fmaxf(mx, fmaxf(src[i], 0.f));
    mx = blkRedMax(mx, red);
    float s = 0.f;
    for (int i = tid; i < N_; i += 256) s += __expf(fmaxf(src[i], 0.f) - mx);
    s = blkRedSum(s, red);
    mx0 = mx; is0 = 1.f / s;
  }
  {
    const float* src = A2 + (size_t)m*N_;
    float mx = 0.f;
    for (int i = tid; i < N_; i += 256) mx = fmaxf(mx, fmaxf(src[i], 0.f));
    mx = blkRedMax(mx, red);
    float s = 0.f;
    for (int i = tid; i < N_; i += 256) s += __expf(fmaxf(src[i], 0.f) - mx);
    s = blkRedSum(s, red);
    mx1 = mx; is1 = 1.f / s;
  }
  const float* s1 = A1 + (size_t)m*N_;
  const float* s2 = A2 + (size_t)m*N_;
  for (int i = tid; i < N_; i += 256) {
    float v1 = __expf(fmaxf(s1[i], 0.f) - mx0) * is0;
    float v2 = __expf(fmaxf(s2[i], 0.f) - mx1) * is1;
    Aout[(size_t)m*N_ + i] = f2bf(v1 + v2);
  }
}

// ---------------- K3: bf16 MFMA batched GEMM ----------------
template<int RELU, int OB16>
__global__ __launch_bounds__(256) void k_gemm_mfma(
    const unsigned short* __restrict__ A, const unsigned short* __restrict__ X,
    void* __restrict__ C, int K, int P)
{
  __shared__ unsigned short sA[128*40];
  __shared__ unsigned short sB[128*40];
  int tid = threadIdx.x, lane = tid & 63, wid = tid >> 6;
  int M = gridDim.y * 128;
  int b = blockIdx.z;
  const unsigned short* Xb = X + (size_t)b*K*P;
  int m0 = blockIdx.y*128, p0 = blockIdx.x*128;
  int wr = wid >> 1, wc = wid & 1;

  f32x4 acc[4][4] = {};

  for (int k0 = 0; k0 < K; k0 += 32) {
    #pragma unroll
    for (int pass = 0; pass < 2; ++pass) {
      int r = (tid >> 2) + 64*pass, kk = (tid & 3)*8;
      short8 v = *(const short8*)&A[(size_t)(m0+r)*K + k0 + kk];
      *(short8*)&sA[r*40 + kk] = v;
    }
    #pragma unroll
    for (int pass = 0; pass < 4; ++pass) {
      int p  = (tid & 63) + 64*(pass & 1);
      int k4 = (tid >> 6)*4 + 16*(pass >> 1);
      ushort4 h;
      h.x = Xb[(size_t)(k0+k4+0)*P + p0 + p];
      h.y = Xb[(size_t)(k0+k4+1)*P + p0 + p];
      h.z = Xb[(size_t)(k0+k4+2)*P + p0 + p];
      h.w = Xb[(size_t)(k0+k4+3)*P + p0 + p];
      *(ushort4*)&sB[p*40 + k4] = h;
    }
    __syncthreads();
    short8 af[4], bf[4];
    #pragma unroll
    for (int f = 0; f < 4; ++f) {
      af[f] = *(const short8*)&sA[(wr*64 + f*16 + (lane & 15))*40 + (lane >> 4)*8];
      bf[f] = *(const short8*)&sB[(wc*64 + f*16 + (lane & 15))*40 + (lane >> 4)*8];
    }
    #pragma unroll
    for (int fm = 0; fm < 4; ++fm)
      #pragma unroll
      for (int fn = 0; fn < 4; ++fn)
        acc[fm][fn] = MFMA16(af[fm], bf[fn], acc[fm][fn]);
    __syncthreads();
  }
  #pragma unroll
  for (int fm = 0; fm < 4; ++fm) {
    int row = m0 + wr*64 + fm*16 + (lane >> 4)*4;
    #pragma unroll
    for (int fn = 0; fn < 4; ++fn) {
      int col = p0 + wc*64 + fn*16 + (lane & 15);
      #pragma unroll
      for (int r = 0; r < 4; ++r) {
        float v = acc[fm][fn][r];
        if (RELU) v = fmaxf(v, 0.f);
        if (OB16) {
          unsigned short* Cb = (unsigned short*)C + (size_t)b*M*P;
          Cb[(size_t)(row + r)*P + col] = f2bf(v);
        } else {
          float* Cb = (float*)C + (size_t)b*M*P;
          Cb[(size_t)(row + r)*P + col] = v;
        }
      }
    }
  }
}

// ---------------- K5: ds temporal-conv block, MFMA, 8 bn per block; bf16 out (in-place) ----
__global__ __launch_bounds__(256) void k_ds3(
    const unsigned short* xds,
    const unsigned short* __restrict__ Wall,
    const float* __restrict__ bi,
    const float* __restrict__ b1m, const float* __restrict__ b1g,
    const float* __restrict__ b2m, const float* __restrict__ b2g,
    const float* __restrict__ bfc,
    unsigned short* outg)
{
  __shared__ unsigned short smem[36352];
  unsigned short* X_lds  = smem;               // [8][14][72]
  unsigned short* xi_lds = smem + 8064;        // [8][14][136]
  unsigned short* fu_lds = smem + 23296;       // [96][136]
  const unsigned short* WiB  = Wall;
  const unsigned short* Wg1B = Wall + 24576;
  const unsigned short* Wg2B = Wall + 49152;
  const unsigned short* WfB  = Wall + 73728;

  int tid = threadIdx.x, lane = tid & 63, wid = tid >> 6;
  int l15 = lane & 15, l4 = lane >> 4;
  int bn0 = blockIdx.x * 8;

  for (int i = tid; i < 8*2*72; i += 256) {
    int g = i / 144, r = i - g*144;
    int tp = (r < 72) ? 0 : 13, c = (r < 72) ? r : r - 72;
    X_lds[(g*14 + tp)*72 + c] = 0;
  }
  for (int i = tid; i < 8*2*136; i += 256) {
    int g = i / 272, r = i - g*272;
    int tp = (r < 136) ? 0 : 13, c = (r < 136) ? r : r - 136;
    xi_lds[(g*14 + tp)*136 + c] = 0;
  }
  for (int i = tid; i < 768; i += 256) {
    int g = i / 96, rem = i - g*96, t = rem >> 3, i8 = rem & 7;
    short8 v = *(const short8*)&xds[(size_t)(bn0+g)*768 + t*64 + i8*8];
    *(short8*)&X_lds[(g*14 + t + 1)*72 + i8*8] = v;
  }
  __syncthreads();

  int ga[6], ta[6];
  #pragma unroll
  for (int mt = 0; mt < 6; ++mt) {
    int r = mt*16 + l15;
    ga[mt] = r / 12; ta[mt] = r - ga[mt]*12;
  }

  {
    f32x4 acc1[6][2] = {};
    int nb = wid*2;
    #pragma unroll
    for (int ks = 0; ks < 6; ++ks) {
      int tap = ks >> 1, i0 = (ks & 1)*32;
      short8 af[6];
      #pragma unroll
      for (int mt = 0; mt < 6; ++mt)
        af[mt] = *(const short8*)&X_lds[(ga[mt]*14 + ta[mt] + tap)*72 + i0 + l4*8];
      short8 bf0 = *(const short8*)&WiB[(size_t)((nb  )*16 + l15)*192 + ks*32 + l4*8];
      short8 bf1 = *(const short8*)&WiB[(size_t)((nb+1)*16 + l15)*192 + ks*32 + l4*8];
      #pragma unroll
      for (int mt = 0; mt < 6; ++mt) {
        acc1[mt][0] = MFMA16(af[mt], bf0, acc1[mt][0]);
        acc1[mt][1] = MFMA16(af[mt], bf1, acc1[mt][1]);
      }
    }
    #pragma unroll
    for (int nn = 0; nn < 2; ++nn) {
      int o = (nb+nn)*16 + l15;
      float bv = bi[o];
      #pragma unroll
      for (int mt = 0; mt < 6; ++mt) {
        #pragma unroll
        for (int reg = 0; reg < 4; ++reg) {
          int r = mt*16 + l4*4 + reg;
          int g = r / 12, t = r - g*12;
          xi_lds[(g*14 + t + 1)*136 + o] = f2bf(acc1[mt][nn][reg] + bv);
        }
      }
    }
  }
  __syncthreads();

  #pragma unroll
  for (int h = 0; h < 2; ++h) {
    const unsigned short* Wg = h ? Wg2B : Wg1B;
    f32x4 am[6] = {}, ag[6] = {};
    #pragma unroll
    for (int ks = 0; ks < 6; ++ks) {
      int tap = ks >> 1, i0 = (ks & 1)*32;
      short8 af[6];
      #pragma unroll
      for (int mt = 0; mt < 6; ++mt)
        af[mt] = *(const short8*)&xi_lds[(ga[mt]*14 + ta[mt] + tap)*136 + h*64 + i0 + l4*8];
      short8 bm = *(const short8*)&Wg[(size_t)(wid*16 + l15)*192 + ks*32 + l4*8];
      short8 bg = *(const short8*)&Wg[(size_t)((wid+4)*16 + l15)*192 + ks*32 + l4*8];
      #pragma unroll
      for (int mt = 0; mt < 6; ++mt) {
        am[mt] = MFMA16(af[mt], bm, am[mt]);
        ag[mt] = MFMA16(af[mt], bg, ag[mt]);
      }
    }
    int o = wid*16 + l15;
    float bmv = (h ? b2m : b1m)[o];
    float bgv = (h ? b2g : b1g)[o];
    #pragma unroll
    for (int mt = 0; mt < 6; ++mt) {
      #pragma unroll
      for (int reg = 0; reg < 4; ++reg) {
        int r = mt*16 + l4*4 + reg;
        int g = r / 12, t = r - g*12;
        float pm = am[mt][reg] + bmv;
        float pg = ag[mt][reg] + bgv;
        float po = pm * sigmoidf_(pg);
        float xi = bf2f(xi_lds[(g*14 + t + 1)*136 + h*64 + o]);
        fu_lds[r*136 + h*64 + o] = f2bf(fmaxf(po + xi, 0.f));
      }
    }
  }
  __syncthreads();

  {
    f32x4 a3[6] = {};
    #pragma unroll
    for (int ks = 0; ks < 4; ++ks) {
      short8 af = *(const short8*)&WfB[(size_t)(wid*16 + l15)*128 + ks*32 + l4*8];
      #pragma unroll
      for (int nt = 0; nt < 6; ++nt) {
        short8 bf = *(const short8*)&fu_lds[(nt*16 + l15)*136 + ks*32 + l4*8];
        a3[nt] = MFMA16(af, bf, a3[nt]);
      }
    }
    int e0 = wid*16 + l4*4;
    float4 bb = *(const float4*)&bfc[e0];
    #pragma unroll
    for (int nt = 0; nt < 6; ++nt) {
      uint2 vv;
      vv.x = f2bf2(a3[nt][0] + bb.x, a3[nt][1] + bb.y);
      vv.y = f2bf2(a3[nt][2] + bb.z, a3[nt][3] + bb.w);
      *(uint2*)&outg[((size_t)(bn0 + ga[nt])*12 + ta[nt])*64 + e0] = vv;
    }
  }
}

// ---------------- K6: attention + FFN + 2x LN; LDS diet -> 3 blocks/CU ------------------
// su: Ybuf[96][72] @0 | Qkv[96][200] @6912 (Hb[96][136] union). partb bf16. shfl-P.
__global__ __launch_bounds__(512) void k_attn5(
    const unsigned short* __restrict__ xg,     // bf16 [BN][12][64]
    const unsigned short* __restrict__ Wat,
    const float* __restrict__ bq, const float* __restrict__ bk, const float* __restrict__ bv,
    const float* __restrict__ bo,
    const float* __restrict__ f1b, const float* __restrict__ f2b,
    const float* __restrict__ g1, const float* __restrict__ be1,
    const float* __restrict__ g2, const float* __restrict__ be2,
    unsigned short* __restrict__ outg)
{
  __shared__ unsigned short su[26112];
  __shared__ unsigned short partb[2][4][96];    // bf16 partials; after stats: [s][0][r] = mu/rs
  unsigned short* Ybuf = su;            // [96][72]
  unsigned short* Qkv  = su + 6912;     // [96][200]
  unsigned short* Hb   = su + 6912;     // [96][136] (union; live only during FF)

  const unsigned short* Wqkv = Wat;
  const unsigned short* Wo   = Wat + 12288;
  const unsigned short* F1   = Wat + 16384;
  const unsigned short* F2   = Wat + 32768;

  int tid = threadIdx.x, lane = tid & 63, w = tid >> 6;
  int l15 = lane & 15, l4 = lane >> 4;
  int wn = w & 3, wm = w >> 2;
  size_t base = (size_t)blockIdx.x * 8 * 768;

  for (int i = tid; i < 768; i += 512) {
    int r = i >> 3, c = i & 7;
    *(short8*)&Ybuf[r*72 + c*8] = *(const short8*)&xg[base + r*64 + c*8];
  }
  __syncthreads();

  // ---- QKV GEMM: Qkv[96][192] ----
  {
    f32x4 acc[3][3] = {};
    #pragma unroll
    for (int ks = 0; ks < 2; ++ks) {
      short8 af[3];
      #pragma unroll
      for (int mi = 0; mi < 3; ++mi)
        af[mi] = *(const short8*)&Ybuf[((wm*3+mi)*16 + l15)*72 + ks*32 + l4*8];
      #pragma unroll
      for (int ni = 0; ni < 3; ++ni) {
        short8 bf = *(const short8*)&Wqkv[(size_t)((wn*3+ni)*16 + l15)*64 + ks*32 + l4*8];
        #pragma unroll
        for (int mi = 0; mi < 3; ++mi)
          acc[mi][ni] = MFMA16(af[mi], bf, acc[mi][ni]);
      }
    }
    #pragma unroll
    for (int ni = 0; ni < 3; ++ni) {
      int col = (wn*3+ni)*16 + l15;
      float bias = col < 64 ? bq[col] : (col < 128 ? bk[col-64] : bv[col-128]);
      #pragma unroll
      for (int mi = 0; mi < 3; ++mi)
        #pragma unroll
        for (int r = 0; r < 4; ++r)
          Qkv[((wm*3+mi)*16 + l4*4 + r)*200 + col] = f2bf(acc[mi][ni][r] + bias);
    }
  }
  __syncthreads();

  // ---- attention: wave w owns bn w; P via shfl (R12-verified); o -> Qkv q-region ----
  {
    int rb = w*12;
    int src0 = (l15 + 32*l4) & 63;
    int src1 = (src0 + 16) & 63;
    #pragma unroll
    for (int h = 0; h < 4; ++h) {
      short8 kf = {}, qf = {};
      if (l4 < 2) {
        kf = *(const short8*)&Qkv[(rb + l15)*200 + 64 + h*16 + l4*8];
        qf = *(const short8*)&Qkv[(rb + l15)*200 +      h*16 + l4*8];
      }
      f32x4 sc = {};
      sc = MFMA16(kf, qf, sc);
      float e[4]; float mx = -3e38f;
      #pragma unroll
      for (int r = 0; r < 4; ++r) {
        float v = (l4 == 3) ? -3e38f : sc[r]*0.25f;
        e[r] = v; mx = fmaxf(mx, v);
      }
      mx = fmaxf(mx, __shfl_xor(mx, 16));
      mx = fmaxf(mx, __shfl_xor(mx, 32));
      float s = 0.f;
      #pragma unroll
      for (int r = 0; r < 4; ++r) { e[r] = __expf(e[r] - mx); s += e[r]; }
      s += __shfl_xor(s, 16); s += __shfl_xor(s, 32);
      float inv = 1.f/s;
      int pk0 = (int)f2bf2(e[0]*inv, e[1]*inv);
      int pk1 = (int)f2bf2(e[2]*inv, e[3]*inv);
      int a0 = __shfl(pk0, src0), b0 = __shfl(pk1, src0);
      int c0 = __shfl(pk0, src1), d0 = __shfl(pk1, src1);
      short8 aaf = {};
      if (l4 < 2) {
        uint4 u = make_uint4((unsigned)a0, (unsigned)b0, (unsigned)c0, (unsigned)d0);
        aaf = __builtin_bit_cast(short8, u);
      }
      short8 vf = {};
      if (l4 < 2) {
        #pragma unroll
        for (int j = 0; j < 8; ++j) {
          int s_ = l4*8 + j;
          vf[j] = (s_ < 12) ? (short)Qkv[(rb + s_)*200 + 128 + h*16 + l15] : (short)0;
        }
      }
      f32x4 o = {};
      o = MFMA16(aaf, vf, o);
      if (l4 < 3) {
        #pragma unroll
        for (int r = 0; r < 4; ++r)
          Qkv[(rb + l4*4 + r)*200 + h*16 + l15] = f2bf(o[r]);   // q-region (dead)
      }
    }
  }
  __syncthreads();

  // ---- WO GEMM (o from Qkv q-region) + residual(Ybuf) + LN1 ----
  {
    f32x4 zacc[3] = {};
    #pragma unroll
    for (int ks = 0; ks < 2; ++ks) {
      short8 bf = *(const short8*)&Wo[(size_t)(wn*16 + l15)*64 + ks*32 + l4*8];
      #pragma unroll
      for (int mi = 0; mi < 3; ++mi) {
        short8 af = *(const short8*)&Qkv[((wm*3+mi)*16 + l15)*200 + ks*32 + l4*8];
        zacc[mi] = MFMA16(af, bf, zacc[mi]);
      }
    }
    int col = wn*16 + l15;
    float bias = bo[col];
    #pragma unroll
    for (int mi = 0; mi < 3; ++mi)
      #pragma unroll
      for (int r = 0; r < 4; ++r) {
        int row = (wm*3+mi)*16 + l4*4 + r;
        float z = zacc[mi][r] + bias + bf2f(Ybuf[row*72 + col]);
        zacc[mi][r] = z;
        float s1 = z, s2 = z*z;
        #pragma unroll
        for (int off = 1; off <= 8; off <<= 1) { s1 += __shfl_xor(s1, off); s2 += __shfl_xor(s2, off); }
        if (l15 == 0) { partb[0][wn][row] = f2bf(s1); partb[1][wn][row] = f2bf(s2); }
      }
    __syncthreads();
    if (tid < 96) {
      float s = bf2f(partb[0][0][tid])+bf2f(partb[0][1][tid])+bf2f(partb[0][2][tid])+bf2f(partb[0][3][tid]);
      float q = bf2f(partb[1][0][tid])+bf2f(partb[1][1][tid])+bf2f(partb[1][2][tid])+bf2f(partb[1][3][tid]);
      float mu = s * (1.f/64.f);
      float var = q * (1.f/64.f) - mu*mu;
      partb[0][0][tid] = f2bf(mu); partb[1][0][tid] = f2bf(rsqrtf(var + 1e-5f));
    }
    __syncthreads();
    float gv = g1[col], bvv = be1[col];
    #pragma unroll
    for (int mi = 0; mi < 3; ++mi)
      #pragma unroll
      for (int r = 0; r < 4; ++r) {
        int row = (wm*3+mi)*16 + l4*4 + r;
        float mu = bf2f(partb[0][0][row]), rs = bf2f(partb[1][0][row]);
        Ybuf[row*72 + col] = f2bf((zacc[mi][r] - mu) * rs * gv + bvv);
      }
  }
  __syncthreads();

  // ---- FFN: two 128-col passes; Hb[96][136] unions Qkv region ----
  {
    f32x4 acc2[3] = {};
    #pragma unroll
    for (int fh = 0; fh < 2; ++fh) {
      // FF1 half: cols fh*128 + [0,128)
      {
        f32x4 acc[3][2] = {};
        #pragma unroll
        for (int ks = 0; ks < 2; ++ks) {
          short8 af[3];
          #pragma unroll
          for (int mi = 0; mi < 3; ++mi)
            af[mi] = *(const short8*)&Ybuf[((wm*3+mi)*16 + l15)*72 + ks*32 + l4*8];
          #pragma unroll
          for (int i = 0; i < 2; ++i) {
            int frow = fh*128 + (wn*2+i)*16 + l15;
            short8 bf = *(const short8*)&F1[(size_t)frow*64 + ks*32 + l4*8];
            #pragma unroll
            for (int mi = 0; mi < 3; ++mi)
              acc[mi][i] = MFMA16(af[mi], bf, acc[mi][i]);
          }
        }
        #pragma unroll
        for (int i = 0; i < 2; ++i) {
          int cl = (wn*2+i)*16 + l15;            // local col 0..127
          float bias = f1b[fh*128 + cl];
          #pragma unroll
          for (int mi = 0; mi < 3; ++mi)
            #pragma unroll
            for (int r = 0; r < 4; ++r)
              Hb[((wm*3+mi)*16 + l4*4 + r)*136 + cl] = f2bf(fmaxf(acc[mi][i][r] + bias, 0.f));
        }
      }
      __syncthreads();
      // FF2 partial over this half's K
      #pragma unroll
      for (int k2 = 0; k2 < 4; ++k2) {
        short8 bf = *(const short8*)&F2[(size_t)(wn*16 + l15)*256 + fh*128 + k2*32 + l4*8];
        #pragma unroll
        for (int mi = 0; mi < 3; ++mi) {
          short8 af = *(const short8*)&Hb[((wm*3+mi)*16 + l15)*136 + k2*32 + l4*8];
          acc2[mi] = MFMA16(af, bf, acc2[mi]);
        }
      }
      if (fh == 0) __syncthreads();
    }
    // residual + LN2 + store
    int col = wn*16 + l15;
    float bias = f2b[col];
    #pragma unroll
    for (int mi = 0; mi < 3; ++mi)
      #pragma unroll
      for (int r = 0; r < 4; ++r) {
        int row = (wm*3+mi)*16 + l4*4 + r;
        float z = acc2[mi][r] + bias + bf2f(Ybuf[row*72 + col]);
        acc2[mi][r] = z;
        float s1 = z, s2 = z*z;
        #pragma unroll
        for (int off = 1; off <= 8; off <<= 1) { s1 += __shfl_xor(s1, off); s2 += __shfl_xor(s2, off); }
        if (l15 == 0) { partb[0][wn][row] = f2bf(s1); partb[1][wn][row] = f2bf(s2); }
      }
    __syncthreads();
    if (tid < 96) {
      float s = bf2f(partb[0][0][tid])+bf2f(partb[0][1][tid])+bf2f(partb[0][2][tid])+bf2f(partb[0][3][tid]);
      float q = bf2f(partb[1][0][tid])+bf2f(partb[1][1][tid])+bf2f(partb[1][2][tid])+bf2f(partb[1][3][tid]);
      float mu = s * (1.f/64.f);
      float var = q * (1.f/64.f) - mu*mu;
      partb[0][0][tid] = f2bf(mu); partb[1][0][tid] = f2bf(rsqrtf(var + 1e-5f));
    }
    __syncthreads();
    float gv = g2[col], bvv = be2[col];
    #pragma unroll
    for (int mi = 0; mi < 3; ++mi)
      #pragma unroll
      for (int r = 0; r < 4; ++r) {
        int row = (wm*3+mi)*16 + l4*4 + r;
        float mu = bf2f(partb[0][0][row]), rs = bf2f(partb[1][0][row]);
        outg[base + row*64 + col] = f2bf((acc2[mi][r] - mu) * rs * gv + bvv);
      }
  }
}

// ---------------- K7: fuse-matrix prep ----------------
__global__ void k_mvec(const float* __restrict__ flow, const float* __restrict__ clw,
                       const float* __restrict__ clb, float* __restrict__ mv)
{
  int n = blockIdx.x*blockDim.x + threadIdx.x;
  if (n < N_) {
    float s = 0.f;
    float bias = clb[0];
    for (int b = 0; b < B_; ++b) {
      const float* f = flow + ((size_t)b*N_ + n)*T_;
      float acc = bias;
      #pragma unroll
      for (int t = 0; t < T_; ++t) acc += f[t]*clw[t];
      s += fmaxf(acc, 0.f);
    }
    mv[n] = s * (1.f/16.f);
  }
}

__global__ void k_fusemat(const float* __restrict__ mv, unsigned short* __restrict__ F)
{
  int idx = blockIdx.x*256 + threadIdx.x;
  int m = idx >> 10, n = idx & 1023;
  float x = 0.5f*(mv[m] + mv[n]);
  F[idx] = f2bf(1.f/(1.f + __expf(-x)));
}

// ---------------- launch ----------------
extern "C" void kernel_launch(void* const* d_in, const int* in_sizes, int n_in,
                              void* d_out, int out_size, void* d_ws, size_t ws_size,
                              hipStream_t stream)
{
  const float* flow = (const float*)d_in[0];
  const int*   day  = (const int*)d_in[1];
  const int*   week = (const int*)d_in[2];
  const float* semb = (const float*)d_in[3];
  const float* demb = (const float*)d_in[4];
  const float* wemb = (const float*)d_in[5];
  const float* gfsw = (const float*)d_in[6];
  const float* gfsb = (const float*)d_in[7];
  const float* gluw = (const float*)d_in[8];
  const float* glub = (const float*)d_in[9];
  const float* gcw  = (const float*)d_in[10];
  const float* gcA  = (const float*)d_in[11];
  const float* gcA2 = (const float*)d_in[12];
  const float* wi   = (const float*)d_in[13];
  const float* bi   = (const float*)d_in[14];
  const float* w1m  = (const float*)d_in[15];
  const float* b1m  = (const float*)d_in[16];
  const float* w1g  = (const float*)d_in[17];
  const float* b1g  = (const float*)d_in[18];
  const float* w2m  = (const float*)d_in[19];
  const float* b2m  = (const float*)d_in[20];
  const float* w2g  = (const float*)d_in[21];
  const float* b2g  = (const float*)d_in[22];
  const float* wfc  = (const float*)d_in[23];
  const float* bfc  = (const float*)d_in[24];
  const float* wq   = (const float*)d_in[25];
  const float* bq   = (const float*)d_in[26];
  const float* wk   = (const float*)d_in[27];
  const float* bk   = (const float*)d_in[28];
  const float* wv   = (const float*)d_in[29];
  const float* bv   = (const float*)d_in[30];
  const float* wo   = (const float*)d_in[31];
  const float* bo   = (const float*)d_in[32];
  const float* f1w  = (const float*)d_in[33];
  const float* f1b  = (const float*)d_in[34];
  const float* f2w  = (const float*)d_in[35];
  const float* f2b  = (const float*)d_in[36];
  const float* g1   = (const float*)d_in[37];
  const float* be1  = (const float*)d_in[38];
  const float* g2   = (const float*)d_in[39];
  const float* be2  = (const float*)d_in[40];
  const float* clw  = (const float*)d_in[41];
  const float* clb  = (const float*)d_in[42];

  float* out = (float*)d_out;
  char* ws = (char*)d_ws;
  unsigned short* Amat = (unsigned short*)ws;                               // 2 MB
  float* mv  = (float*)(ws + (size_t)2*1024*1024);                          // 64 KB region
  unsigned short* wTe = (unsigned short*)(ws + (size_t)2*1024*1024 + 64*1024); // 64 KB region
  unsigned short* wds = (unsigned short*)(ws + (size_t)2*1024*1024 + 128*1024); // 192 KB region
  unsigned short* wat = (unsigned short*)(ws + (size_t)2*1024*1024 + 320*1024); // 128 KB region
  unsigned short* xw  = (unsigned short*)(ws + (size_t)3*1024*1024);        // 24 MB
  unsigned short* xds = (unsigned short*)(ws + (size_t)28*1024*1024);       // 24 MB

  k_wprep_all<<<192, 256, 0, stream>>>(gfsw, gluw, gcw,
                                       wi, w1m, w1g, w2m, w2g, wfc,
                                       wq, wk, wv, wo, f1w, f2w,
                                       wTe, wds, wat);
  // xw = GLU(gfs_fc(embed)) @ gc_weight -> bf16   (full MFMA)
  k_embed3<<<BNT/128, 256, 0, stream>>>(flow, day, week, semb, demb, wemb,
                                        wTe, gfsb, glub, xw);
  // combined adjacency (bf16)
  k_aprep<<<N_, 256, 0, stream>>>(gcA, gcA2, Amat);
  // xds = relu(A @ xw) -> bf16
  dim3 gg(TD/128, N_/128, B_);
  k_gemm_mfma<1,1><<<gg, 256, 0, stream>>>(Amat, xw, xds, N_, TD);
  // ds block (MFMA) -> bf16, in-place on xds
  k_ds3<<<BN_/8, 256, 0, stream>>>(xds, wds, bi, b1m, b1g, b2m, b2g, bfc, xds);
  // y2 = attn+ffn block (MFMA, 3 blocks/CU) -> bf16 (reuse xw region)
  k_attn5<<<BN_/8, 512, 0, stream>>>(xds, wat, bq, bk, bv, bo, f1b, f2b,
                                     g1, be1, g2, be2, xw);
  // fuse matrix (bf16, reuse Amat region)
  k_mvec<<<N_/256, 256, 0, stream>>>(flow, clw, clb, mv);
  k_fusemat<<<(N_*N_)/256, 256, 0, stream>>>(mv, Amat);
  // out = fuse @ y2 -> d_out (fp32)
  k_gemm_mfma<0,0><<<gg, 256, 0, stream>>>(Amat, xw, out, N_, TD);
}

// Round 16
// 328.080 us; speedup vs baseline: 1.0407x; 1.0046x over previous
//
#include <hip/hip_runtime.h>
#include <hip/hip_bf16.h>
#include <cstdint>

#define B_ 16
#define N_ 1024
#define T_ 12
#define HD 64
#define BN_ (B_*N_)     // 16384
#define BNT (B_*N_*T_)  // 196608
#define TD (T_*HD)      // 768

typedef __attribute__((ext_vector_type(8))) short short8;
typedef __attribute__((ext_vector_type(4))) float f32x4;

#define MFMA16(a,b,c) __builtin_amdgcn_mfma_f32_16x16x32_bf16(a,b,c,0,0,0)

__device__ __forceinline__ float sigmoidf_(float x) { return 1.f / (1.f + __expf(-x)); }

__device__ __forceinline__ unsigned short f2bf(float f) {
  __hip_bfloat16 h = __float2bfloat16(f);
  return __builtin_bit_cast(unsigned short, h);
}
__device__ __forceinline__ unsigned int f2bf2(float lo, float hi) {
  return (unsigned int)f2bf(lo) | ((unsigned int)f2bf(hi) << 16);
}
__device__ __forceinline__ float bf2f(unsigned short h) {
  unsigned int u = ((unsigned int)h) << 16;
  return __uint_as_float(u);
}

// ---------------- reductions ----------------
__device__ __forceinline__ float blkRedMax(float v, float* red) {
  #pragma unroll
  for (int off = 32; off >= 1; off >>= 1) v = fmaxf(v, __shfl_xor(v, off));
  int w = threadIdx.x >> 6;
  if ((threadIdx.x & 63) == 0) red[w] = v;
  __syncthreads();
  v = fmaxf(fmaxf(red[0], red[1]), fmaxf(red[2], red[3]));
  __syncthreads();
  return v;
}
__device__ __forceinline__ float blkRedSum(float v, float* red) {
  #pragma unroll
  for (int off = 32; off >= 1; off >>= 1) v += __shfl_xor(v, off);
  int w = threadIdx.x >> 6;
  if ((threadIdx.x & 63) == 0) red[w] = v;
  __syncthreads();
  v = red[0] + red[1] + red[2] + red[3];
  __syncthreads();
  return v;
}

// ---------------- K-wprep-all: fused weight prep (embed + ds + attn) ----------------
__global__ void k_wprep_all(
    const float* __restrict__ w1, const float* __restrict__ w2, const float* __restrict__ gcw,
    const float* __restrict__ wi,
    const float* __restrict__ w1m, const float* __restrict__ w1g,
    const float* __restrict__ w2m, const float* __restrict__ w2g,
    const float* __restrict__ wfc,
    const float* __restrict__ wq, const float* __restrict__ wk,
    const float* __restrict__ wv, const float* __restrict__ wo,
    const float* __restrict__ f1w, const float* __restrict__ f2w,
    unsigned short* __restrict__ wTe, unsigned short* __restrict__ wds,
    unsigned short* __restrict__ wat)
{
  int t = blockIdx.x*256 + threadIdx.x;   // 192*256 = 49152
  if (t < 4096)        wat[t] = f2bf(wq[t]);
  else if (t < 8192)   wat[t] = f2bf(wk[t-4096]);
  else if (t < 12288)  wat[t] = f2bf(wv[t-8192]);
  else if (t < 16384)  wat[t] = f2bf(wo[t-12288]);
  else if (t < 32768)  wat[t] = f2bf(f1w[t-16384]);
  else                 wat[t] = f2bf(f2w[t-32768]);
  if (t < 4096)       wTe[t] = f2bf(w1[t]);
  else if (t < 12288) wTe[t] = f2bf(w2[t-4096]);
  else if (t < 16384) {
    int r = t - 12288, e = r >> 6, d = r & 63;
    wTe[12288 + e*64 + d] = f2bf(gcw[d*64 + e]);
  }
  if (t < 24576) {
    int o = t / 192, k = t - o*192, tap = k >> 6, i = k & 63;
    wds[o*192 + k] = f2bf(wi[(o*64 + i)*3 + tap]);
  }
  if (t < 12288) {
    int o = t / 192, k = t - o*192, tap = k >> 6, i = k & 63;
    int src = (o*64 + i)*3 + tap;
    wds[24576 + o*192 + k]      = f2bf(w1m[src]);
    wds[24576 + (64+o)*192 + k] = f2bf(w1g[src]);
    wds[49152 + o*192 + k]      = f2bf(w2m[src]);
    wds[49152 + (64+o)*192 + k] = f2bf(w2g[src]);
  }
  if (t < 8192) wds[73728 + t] = f2bf(wfc[t]);
}

// ---------------- K1: embed + gfs_fc + GLU + (x @ gc_weight), full MFMA ----------------
__global__ __launch_bounds__(256) void k_embed3(
    const float* __restrict__ flow, const int* __restrict__ day, const int* __restrict__ week,
    const float* __restrict__ semb, const float* __restrict__ demb, const float* __restrict__ wemb,
    const unsigned short* __restrict__ wTe, const float* __restrict__ b1,
    const float* __restrict__ b2,
    unsigned short* __restrict__ outw)
{
  __shared__ unsigned short sEa[128*72];
  __shared__ unsigned short sEb[128*72];
  const unsigned short* W1  = wTe;
  const unsigned short* W2  = wTe + 4096;
  const unsigned short* GcT = wTe + 12288;

  int tid = threadIdx.x, lane = tid & 63, w = tid >> 6;
  int l15 = lane & 15, l4 = lane >> 4;
  int row0 = blockIdx.x * 128;

  for (int i = tid; i < 8192; i += 256) {
    int r = i >> 6, c = i & 63;
    int row = row0 + r;
    int n = (row / T_) & (N_-1);
    float val;
    if (c == 0)      val = flow[row];
    else if (c < 33) val = semb[n*32 + (c-1)];
    else if (c < 49) val = demb[day[row]*16 + (c-33)];
    else             val = wemb[week[row]*15 + (c-49)];
    sEa[r*72 + c] = f2bf(val);
  }
  __syncthreads();

  {
    f32x4 acc[8] = {};
    #pragma unroll
    for (int ks = 0; ks < 2; ++ks) {
      short8 bf = *(const short8*)&W1[(w*16 + l15)*64 + ks*32 + l4*8];
      #pragma unroll
      for (int mt = 0; mt < 8; ++mt) {
        short8 af = *(const short8*)&sEa[(mt*16 + l15)*72 + ks*32 + l4*8];
        acc[mt] = MFMA16(af, bf, acc[mt]);
      }
    }
    float bias = b1[w*16 + l15];
    #pragma unroll
    for (int mt = 0; mt < 8; ++mt)
      #pragma unroll
      for (int r = 0; r < 4; ++r)
        sEb[(mt*16 + l4*4 + r)*72 + w*16 + l15] = f2bf(acc[mt][r] + bias);
  }
  __syncthreads();

  {
    f32x4 alo[8] = {}, ahi[8] = {};
    #pragma unroll
    for (int ks = 0; ks < 2; ++ks) {
      short8 blo = *(const short8*)&W2[(size_t)(w*16 + l15)*64 + ks*32 + l4*8];
      short8 bhi = *(const short8*)&W2[(size_t)(64 + w*16 + l15)*64 + ks*32 + l4*8];
      #pragma unroll
      for (int mt = 0; mt < 8; ++mt) {
        short8 af = *(const short8*)&sEb[(mt*16 + l15)*72 + ks*32 + l4*8];
        alo[mt] = MFMA16(af, blo, alo[mt]);
        ahi[mt] = MFMA16(af, bhi, ahi[mt]);
      }
    }
    float blov = b2[w*16 + l15], bhiv = b2[64 + w*16 + l15];
    #pragma unroll
    for (int mt = 0; mt < 8; ++mt)
      #pragma unroll
      for (int r = 0; r < 4; ++r) {
        float v = (alo[mt][r] + blov) * sigmoidf_(ahi[mt][r] + bhiv);
        sEa[(mt*16 + l4*4 + r)*72 + w*16 + l15] = f2bf(v);
      }
  }
  __syncthreads();

  {
    f32x4 acc[8] = {};
    #pragma unroll
    for (int ks = 0; ks < 2; ++ks) {
      short8 bf = *(const short8*)&GcT[(w*16 + l15)*64 + ks*32 + l4*8];
      #pragma unroll
      for (int mt = 0; mt < 8; ++mt) {
        short8 af = *(const short8*)&sEa[(mt*16 + l15)*72 + ks*32 + l4*8];
        acc[mt] = MFMA16(af, bf, acc[mt]);
      }
    }
    #pragma unroll
    for (int mt = 0; mt < 8; ++mt)
      #pragma unroll
      for (int r = 0; r < 4; ++r)
        outw[(size_t)(row0 + mt*16 + l4*4 + r)*64 + w*16 + l15] = f2bf(acc[mt][r]);
  }
}

// ---------------- K2: A = softmax(relu(A1),1) + softmax(relu(A2),1), bf16 out ------------
__global__ __launch_bounds__(256) void k_aprep(
    const float* __restrict__ A1, const float* __restrict__ A2, unsigned short* __restrict__ Aout)
{
  __shared__ float red[4];
  int m = blockIdx.x, tid = threadIdx.x;
  float mx0, is0, mx1, is1;
  {
    const float* src = A1 + (size_t)m*N_;
    float mx = 0.f;
    for (int i = tid; i < N_; i += 256) mx = fmaxf(mx, fmaxf(src[i], 0.f));
    mx = blkRedMax(mx, red);
    float s = 0.f;
    for (int i = tid; i < N_; i += 256) s += __expf(fmaxf(src[i], 0.f) - mx);
    s = blkRedSum(s, red);
    mx0 = mx; is0 = 1.f / s;
  }
  {
    const float* src = A2 + (size_t)m*N_;
    float mx = 0.f;
    for (int i = tid; i < N_; i += 256) mx = fmaxf(mx, fmaxf(src[i], 0.f));
    mx = blkRedMax(mx, red);
    float s = 0.f;
    for (int i = tid; i < N_; i += 256) s += __expf(fmaxf(src[i], 0.f) - mx);
    s = blkRedSum(s, red);
    mx1 = mx; is1 = 1.f / s;
  }
  const float* s1 = A1 + (size_t)m*N_;
  const float* s2 = A2 + (size_t)m*N_;
  for (int i = tid; i < N_; i += 256) {
    float v1 = __expf(fmaxf(s1[i], 0.f) - mx0) * is0;
    float v2 = __expf(fmaxf(s2[i], 0.f) - mx1) * is1;
    Aout[(size_t)m*N_ + i] = f2bf(v1 + v2);
  }
}

// ---------------- K3: bf16 MFMA batched GEMM ----------------
template<int RELU, int OB16>
__global__ __launch_bounds__(256) void k_gemm_mfma(
    const unsigned short* __restrict__ A, const unsigned short* __restrict__ X,
    void* __restrict__ C, int K, int P)
{
  __shared__ unsigned short sA[128*40];
  __shared__ unsigned short sB[128*40];
  int tid = threadIdx.x, lane = tid & 63, wid = tid >> 6;
  int M = gridDim.y * 128;
  int b = blockIdx.z;
  const unsigned short* Xb = X + (size_t)b*K*P;
  int m0 = blockIdx.y*128, p0 = blockIdx.x*128;
  int wr = wid >> 1, wc = wid & 1;

  f32x4 acc[4][4] = {};

  for (int k0 = 0; k0 < K; k0 += 32) {
    #pragma unroll
    for (int pass = 0; pass < 2; ++pass) {
      int r = (tid >> 2) + 64*pass, kk = (tid & 3)*8;
      short8 v = *(const short8*)&A[(size_t)(m0+r)*K + k0 + kk];
      *(short8*)&sA[r*40 + kk] = v;
    }
    #pragma unroll
    for (int pass = 0; pass < 4; ++pass) {
      int p  = (tid & 63) + 64*(pass & 1);
      int k4 = (tid >> 6)*4 + 16*(pass >> 1);
      ushort4 h;
      h.x = Xb[(size_t)(k0+k4+0)*P + p0 + p];
      h.y = Xb[(size_t)(k0+k4+1)*P + p0 + p];
      h.z = Xb[(size_t)(k0+k4+2)*P + p0 + p];
      h.w = Xb[(size_t)(k0+k4+3)*P + p0 + p];
      *(ushort4*)&sB[p*40 + k4] = h;
    }
    __syncthreads();
    short8 af[4], bf[4];
    #pragma unroll
    for (int f = 0; f < 4; ++f) {
      af[f] = *(const short8*)&sA[(wr*64 + f*16 + (lane & 15))*40 + (lane >> 4)*8];
      bf[f] = *(const short8*)&sB[(wc*64 + f*16 + (lane & 15))*40 + (lane >> 4)*8];
    }
    #pragma unroll
    for (int fm = 0; fm < 4; ++fm)
      #pragma unroll
      for (int fn = 0; fn < 4; ++fn)
        acc[fm][fn] = MFMA16(af[fm], bf[fn], acc[fm][fn]);
    __syncthreads();
  }
  #pragma unroll
  for (int fm = 0; fm < 4; ++fm) {
    int row = m0 + wr*64 + fm*16 + (lane >> 4)*4;
    #pragma unroll
    for (int fn = 0; fn < 4; ++fn) {
      int col = p0 + wc*64 + fn*16 + (lane & 15);
      #pragma unroll
      for (int r = 0; r < 4; ++r) {
        float v = acc[fm][fn][r];
        if (RELU) v = fmaxf(v, 0.f);
        if (OB16) {
          unsigned short* Cb = (unsigned short*)C + (size_t)b*M*P;
          Cb[(size_t)(row + r)*P + col] = f2bf(v);
        } else {
          float* Cb = (float*)C + (size_t)b*M*P;
          Cb[(size_t)(row + r)*P + col] = v;
        }
      }
    }
  }
}

// ---------------- K5: ds temporal-conv block, MFMA, 8 bn per block; bf16 out (in-place) ----
__global__ __launch_bounds__(256) void k_ds3(
    const unsigned short* xds,
    const unsigned short* __restrict__ Wall,
    const float* __restrict__ bi,
    const float* __restrict__ b1m, const float* __restrict__ b1g,
    const float* __restrict__ b2m, const float* __restrict__ b2g,
    const float* __restrict__ bfc,
    unsigned short* outg)
{
  __shared__ unsigned short smem[36352];
  unsigned short* X_lds  = smem;               // [8][14][72]
  unsigned short* xi_lds = smem + 8064;        // [8][14][136]
  unsigned short* fu_lds = smem + 23296;       // [96][136]
  const unsigned short* WiB  = Wall;
  const unsigned short* Wg1B = Wall + 24576;
  const unsigned short* Wg2B = Wall + 49152;
  const unsigned short* WfB  = Wall + 73728;

  int tid = threadIdx.x, lane = tid & 63, wid = tid >> 6;
  int l15 = lane & 15, l4 = lane >> 4;
  int bn0 = blockIdx.x * 8;

  for (int i = tid; i < 8*2*72; i += 256) {
    int g = i / 144, r = i - g*144;
    int tp = (r < 72) ? 0 : 13, c = (r < 72) ? r : r - 72;
    X_lds[(g*14 + tp)*72 + c] = 0;
  }
  for (int i = tid; i < 8*2*136; i += 256) {
    int g = i / 272, r = i - g*272;
    int tp = (r < 136) ? 0 : 13, c = (r < 136) ? r : r - 136;
    xi_lds[(g*14 + tp)*136 + c] = 0;
  }
  for (int i = tid; i < 768; i += 256) {
    int g = i / 96, rem = i - g*96, t = rem >> 3, i8 = rem & 7;
    short8 v = *(const short8*)&xds[(size_t)(bn0+g)*768 + t*64 + i8*8];
    *(short8*)&X_lds[(g*14 + t + 1)*72 + i8*8] = v;
  }
  __syncthreads();

  int ga[6], ta[6];
  #pragma unroll
  for (int mt = 0; mt < 6; ++mt) {
    int r = mt*16 + l15;
    ga[mt] = r / 12; ta[mt] = r - ga[mt]*12;
  }

  {
    f32x4 acc1[6][2] = {};
    int nb = wid*2;
    #pragma unroll
    for (int ks = 0; ks < 6; ++ks) {
      int tap = ks >> 1, i0 = (ks & 1)*32;
      short8 af[6];
      #pragma unroll
      for (int mt = 0; mt < 6; ++mt)
        af[mt] = *(const short8*)&X_lds[(ga[mt]*14 + ta[mt] + tap)*72 + i0 + l4*8];
      short8 bf0 = *(const short8*)&WiB[(size_t)((nb  )*16 + l15)*192 + ks*32 + l4*8];
      short8 bf1 = *(const short8*)&WiB[(size_t)((nb+1)*16 + l15)*192 + ks*32 + l4*8];
      #pragma unroll
      for (int mt = 0; mt < 6; ++mt) {
        acc1[mt][0] = MFMA16(af[mt], bf0, acc1[mt][0]);
        acc1[mt][1] = MFMA16(af[mt], bf1, acc1[mt][1]);
      }
    }
    #pragma unroll
    for (int nn = 0; nn < 2; ++nn) {
      int o = (nb+nn)*16 + l15;
      float bv = bi[o];
      #pragma unroll
      for (int mt = 0; mt < 6; ++mt) {
        #pragma unroll
        for (int reg = 0; reg < 4; ++reg) {
          int r = mt*16 + l4*4 + reg;
          int g = r / 12, t = r - g*12;
          xi_lds[(g*14 + t + 1)*136 + o] = f2bf(acc1[mt][nn][reg] + bv);
        }
      }
    }
  }
  __syncthreads();

  #pragma unroll
  for (int h = 0; h < 2; ++h) {
    const unsigned short* Wg = h ? Wg2B : Wg1B;
    f32x4 am[6] = {}, ag[6] = {};
    #pragma unroll
    for (int ks = 0; ks < 6; ++ks) {
      int tap = ks >> 1, i0 = (ks & 1)*32;
      short8 af[6];
      #pragma unroll
      for (int mt = 0; mt < 6; ++mt)
        af[mt] = *(const short8*)&xi_lds[(ga[mt]*14 + ta[mt] + tap)*136 + h*64 + i0 + l4*8];
      short8 bm = *(const short8*)&Wg[(size_t)(wid*16 + l15)*192 + ks*32 + l4*8];
      short8 bg = *(const short8*)&Wg[(size_t)((wid+4)*16 + l15)*192 + ks*32 + l4*8];
      #pragma unroll
      for (int mt = 0; mt < 6; ++mt) {
        am[mt] = MFMA16(af[mt], bm, am[mt]);
        ag[mt] = MFMA16(af[mt], bg, ag[mt]);
      }
    }
    int o = wid*16 + l15;
    float bmv = (h ? b2m : b1m)[o];
    float bgv = (h ? b2g : b1g)[o];
    #pragma unroll
    for (int mt = 0; mt < 6; ++mt) {
      #pragma unroll
      for (int reg = 0; reg < 4; ++reg) {
        int r = mt*16 + l4*4 + reg;
        int g = r / 12, t = r - g*12;
        float pm = am[mt][reg] + bmv;
        float pg = ag[mt][reg] + bgv;
        float po = pm * sigmoidf_(pg);
        float xi = bf2f(xi_lds[(g*14 + t + 1)*136 + h*64 + o]);
        fu_lds[r*136 + h*64 + o] = f2bf(fmaxf(po + xi, 0.f));
      }
    }
  }
  __syncthreads();

  {
    f32x4 a3[6] = {};
    #pragma unroll
    for (int ks = 0; ks < 4; ++ks) {
      short8 af = *(const short8*)&WfB[(size_t)(wid*16 + l15)*128 + ks*32 + l4*8];
      #pragma unroll
      for (int nt = 0; nt < 6; ++nt) {
        short8 bf = *(const short8*)&fu_lds[(nt*16 + l15)*136 + ks*32 + l4*8];
        a3[nt] = MFMA16(af, bf, a3[nt]);
      }
    }
    int e0 = wid*16 + l4*4;
    float4 bb = *(const float4*)&bfc[e0];
    #pragma unroll
    for (int nt = 0; nt < 6; ++nt) {
      uint2 vv;
      vv.x = f2bf2(a3[nt][0] + bb.x, a3[nt][1] + bb.y);
      vv.y = f2bf2(a3[nt][2] + bb.z, a3[nt][3] + bb.w);
      *(uint2*)&outg[((size_t)(bn0 + ga[nt])*12 + ta[nt])*64 + e0] = vv;
    }
  }
}

// ---------------- K6: attention + FFN + 2x LN; launch_bounds(512,4) for ILP -------------
// su: Ybuf[96][72] @0 | Qkv[96][200] @6912 (Hb[96][136] union). partb bf16. shfl-P.
__global__ __launch_bounds__(512, 4) void k_attn5(
    const unsigned short* __restrict__ xg,     // bf16 [BN][12][64]
    const unsigned short* __restrict__ Wat,
    const float* __restrict__ bq, const float* __restrict__ bk, const float* __restrict__ bv,
    const float* __restrict__ bo,
    const float* __restrict__ f1b, const float* __restrict__ f2b,
    const float* __restrict__ g1, const float* __restrict__ be1,
    const float* __restrict__ g2, const float* __restrict__ be2,
    unsigned short* __restrict__ outg)
{
  __shared__ unsigned short su[26112];
  __shared__ unsigned short partb[2][4][96];    // bf16 partials; after stats: [s][0][r] = mu/rs
  unsigned short* Ybuf = su;            // [96][72]
  unsigned short* Qkv  = su + 6912;     // [96][200]
  unsigned short* Hb   = su + 6912;     // [96][136] (union; live only during FF)

  const unsigned short* Wqkv = Wat;
  const unsigned short* Wo   = Wat + 12288;
  const unsigned short* F1   = Wat + 16384;
  const unsigned short* F2   = Wat + 32768;

  int tid = threadIdx.x, lane = tid & 63, w = tid >> 6;
  int l15 = lane & 15, l4 = lane >> 4;
  int wn = w & 3, wm = w >> 2;
  size_t base = (size_t)blockIdx.x * 8 * 768;

  for (int i = tid; i < 768; i += 512) {
    int r = i >> 3, c = i & 7;
    *(short8*)&Ybuf[r*72 + c*8] = *(const short8*)&xg[base + r*64 + c*8];
  }
  __syncthreads();

  // ---- QKV GEMM: Qkv[96][192] ----
  {
    f32x4 acc[3][3] = {};
    #pragma unroll
    for (int ks = 0; ks < 2; ++ks) {
      short8 af[3];
      #pragma unroll
      for (int mi = 0; mi < 3; ++mi)
        af[mi] = *(const short8*)&Ybuf[((wm*3+mi)*16 + l15)*72 + ks*32 + l4*8];
      #pragma unroll
      for (int ni = 0; ni < 3; ++ni) {
        short8 bf = *(const short8*)&Wqkv[(size_t)((wn*3+ni)*16 + l15)*64 + ks*32 + l4*8];
        #pragma unroll
        for (int mi = 0; mi < 3; ++mi)
          acc[mi][ni] = MFMA16(af[mi], bf, acc[mi][ni]);
      }
    }
    #pragma unroll
    for (int ni = 0; ni < 3; ++ni) {
      int col = (wn*3+ni)*16 + l15;
      float bias = col < 64 ? bq[col] : (col < 128 ? bk[col-64] : bv[col-128]);
      #pragma unroll
      for (int mi = 0; mi < 3; ++mi)
        #pragma unroll
        for (int r = 0; r < 4; ++r)
          Qkv[((wm*3+mi)*16 + l4*4 + r)*200 + col] = f2bf(acc[mi][ni][r] + bias);
    }
  }
  __syncthreads();

  // ---- attention: wave w owns bn w; P via shfl; o -> Qkv q-region ----
  {
    int rb = w*12;
    int src0 = (l15 + 32*l4) & 63;
    int src1 = (src0 + 16) & 63;
    #pragma unroll
    for (int h = 0; h < 4; ++h) {
      short8 kf = {}, qf = {};
      if (l4 < 2) {
        kf = *(const short8*)&Qkv[(rb + l15)*200 + 64 + h*16 + l4*8];
        qf = *(const short8*)&Qkv[(rb + l15)*200 +      h*16 + l4*8];
      }
      f32x4 sc = {};
      sc = MFMA16(kf, qf, sc);
      float e[4]; float mx = -3e38f;
      #pragma unroll
      for (int r = 0; r < 4; ++r) {
        float v = (l4 == 3) ? -3e38f : sc[r]*0.25f;
        e[r] = v; mx = fmaxf(mx, v);
      }
      mx = fmaxf(mx, __shfl_xor(mx, 16));
      mx = fmaxf(mx, __shfl_xor(mx, 32));
      float s = 0.f;
      #pragma unroll
      for (int r = 0; r < 4; ++r) { e[r] = __expf(e[r] - mx); s += e[r]; }
      s += __shfl_xor(s, 16); s += __shfl_xor(s, 32);
      float inv = 1.f/s;
      int pk0 = (int)f2bf2(e[0]*inv, e[1]*inv);
      int pk1 = (int)f2bf2(e[2]*inv, e[3]*inv);
      int a0 = __shfl(pk0, src0), b0 = __shfl(pk1, src0);
      int c0 = __shfl(pk0, src1), d0 = __shfl(pk1, src1);
      short8 aaf = {};
      if (l4 < 2) {
        uint4 u = make_uint4((unsigned)a0, (unsigned)b0, (unsigned)c0, (unsigned)d0);
        aaf = __builtin_bit_cast(short8, u);
      }
      short8 vf = {};
      if (l4 < 2) {
        #pragma unroll
        for (int j = 0; j < 8; ++j) {
          int s_ = l4*8 + j;
          vf[j] = (s_ < 12) ? (short)Qkv[(rb + s_)*200 + 128 + h*16 + l15] : (short)0;
        }
      }
      f32x4 o = {};
      o = MFMA16(aaf, vf, o);
      if (l4 < 3) {
        #pragma unroll
        for (int r = 0; r < 4; ++r)
          Qkv[(rb + l4*4 + r)*200 + h*16 + l15] = f2bf(o[r]);   // q-region (dead)
      }
    }
  }
  __syncthreads();

  // ---- WO GEMM (o from Qkv q-region) + residual(Ybuf) + LN1 ----
  {
    f32x4 zacc[3] = {};
    #pragma unroll
    for (int ks = 0; ks < 2; ++ks) {
      short8 bf = *(const short8*)&Wo[(size_t)(wn*16 + l15)*64 + ks*32 + l4*8];
      #pragma unroll
      for (int mi = 0; mi < 3; ++mi) {
        short8 af = *(const short8*)&Qkv[((wm*3+mi)*16 + l15)*200 + ks*32 + l4*8];
        zacc[mi] = MFMA16(af, bf, zacc[mi]);
      }
    }
    int col = wn*16 + l15;
    float bias = bo[col];
    #pragma unroll
    for (int mi = 0; mi < 3; ++mi)
      #pragma unroll
      for (int r = 0; r < 4; ++r) {
        int row = (wm*3+mi)*16 + l4*4 + r;
        float z = zacc[mi][r] + bias + bf2f(Ybuf[row*72 + col]);
        zacc[mi][r] = z;
        float s1 = z, s2 = z*z;
        #pragma unroll
        for (int off = 1; off <= 8; off <<= 1) { s1 += __shfl_xor(s1, off); s2 += __shfl_xor(s2, off); }
        if (l15 == 0) { partb[0][wn][row] = f2bf(s1); partb[1][wn][row] = f2bf(s2); }
      }
    __syncthreads();
    if (tid < 96) {
      float s = bf2f(partb[0][0][tid])+bf2f(partb[0][1][tid])+bf2f(partb[0][2][tid])+bf2f(partb[0][3][tid]);
      float q = bf2f(partb[1][0][tid])+bf2f(partb[1][1][tid])+bf2f(partb[1][2][tid])+bf2f(partb[1][3][tid]);
      float mu = s * (1.f/64.f);
      float var = q * (1.f/64.f) - mu*mu;
      partb[0][0][tid] = f2bf(mu); partb[1][0][tid] = f2bf(rsqrtf(var + 1e-5f));
    }
    __syncthreads();
    float gv = g1[col], bvv = be1[col];
    #pragma unroll
    for (int mi = 0; mi < 3; ++mi)
      #pragma unroll
      for (int r = 0; r < 4; ++r) {
        int row = (wm*3+mi)*16 + l4*4 + r;
        float mu = bf2f(partb[0][0][row]), rs = bf2f(partb[1][0][row]);
        Ybuf[row*72 + col] = f2bf((zacc[mi][r] - mu) * rs * gv + bvv);
      }
  }
  __syncthreads();

  // ---- FFN: two 128-col passes; Hb[96][136] unions Qkv region ----
  {
    f32x4 acc2[3] = {};
    #pragma unroll
    for (int fh = 0; fh < 2; ++fh) {
      {
        f32x4 acc[3][2] = {};
        #pragma unroll
        for (int ks = 0; ks < 2; ++ks) {
          short8 af[3];
          #pragma unroll
          for (int mi = 0; mi < 3; ++mi)
            af[mi] = *(const short8*)&Ybuf[((wm*3+mi)*16 + l15)*72 + ks*32 + l4*8];
          #pragma unroll
          for (int i = 0; i < 2; ++i) {
            int frow = fh*128 + (wn*2+i)*16 + l15;
            short8 bf = *(const short8*)&F1[(size_t)frow*64 + ks*32 + l4*8];
            #pragma unroll
            for (int mi = 0; mi < 3; ++mi)
              acc[mi][i] = MFMA16(af[mi], bf, acc[mi][i]);
          }
        }
        #pragma unroll
        for (int i = 0; i < 2; ++i) {
          int cl = (wn*2+i)*16 + l15;            // local col 0..127
          float bias = f1b[fh*128 + cl];
          #pragma unroll
          for (int mi = 0; mi < 3; ++mi)
            #pragma unroll
            for (int r = 0; r < 4; ++r)
              Hb[((wm*3+mi)*16 + l4*4 + r)*136 + cl] = f2bf(fmaxf(acc[mi][i][r] + bias, 0.f));
        }
      }
      __syncthreads();
      #pragma unroll
      for (int k2 = 0; k2 < 4; ++k2) {
        short8 bf = *(const short8*)&F2[(size_t)(wn*16 + l15)*256 + fh*128 + k2*32 + l4*8];
        #pragma unroll
        for (int mi = 0; mi < 3; ++mi) {
          short8 af = *(const short8*)&Hb[((wm*3+mi)*16 + l15)*136 + k2*32 + l4*8];
          acc2[mi] = MFMA16(af, bf, acc2[mi]);
        }
      }
      if (fh == 0) __syncthreads();
    }
    int col = wn*16 + l15;
    float bias = f2b[col];
    #pragma unroll
    for (int mi = 0; mi < 3; ++mi)
      #pragma unroll
      for (int r = 0; r < 4; ++r) {
        int row = (wm*3+mi)*16 + l4*4 + r;
        float z = acc2[mi][r] + bias + bf2f(Ybuf[row*72 + col]);
        acc2[mi][r] = z;
        float s1 = z, s2 = z*z;
        #pragma unroll
        for (int off = 1; off <= 8; off <<= 1) { s1 += __shfl_xor(s1, off); s2 += __shfl_xor(s2, off); }
        if (l15 == 0) { partb[0][wn][row] = f2bf(s1); partb[1][wn][row] = f2bf(s2); }
      }
    __syncthreads();
    if (tid < 96) {
      float s = bf2f(partb[0][0][tid])+bf2f(partb[0][1][tid])+bf2f(partb[0][2][tid])+bf2f(partb[0][3][tid]);
      float q = bf2f(partb[1][0][tid])+bf2f(partb[1][1][tid])+bf2f(partb[1][2][tid])+bf2f(partb[1][3][tid]);
      float mu = s * (1.f/64.f);
      float var = q * (1.f/64.f) - mu*mu;
      partb[0][0][tid] = f2bf(mu); partb[1][0][tid] = f2bf(rsqrtf(var + 1e-5f));
    }
    __syncthreads();
    float gv = g2[col], bvv = be2[col];
    #pragma unroll
    for (int mi = 0; mi < 3; ++mi)
      #pragma unroll
      for (int r = 0; r < 4; ++r) {
        int row = (wm*3+mi)*16 + l4*4 + r;
        float mu = bf2f(partb[0][0][row]), rs = bf2f(partb[1][0][row]);
        outg[base + row*64 + col] = f2bf((acc2[mi][r] - mu) * rs * gv + bvv);
      }
  }
}

// ---------------- K7: fuse-matrix prep ----------------
__global__ void k_mvec(const float* __restrict__ flow, const float* __restrict__ clw,
                       const float* __restrict__ clb, float* __restrict__ mv)
{
  int n = blockIdx.x*blockDim.x + threadIdx.x;
  if (n < N_) {
    float s = 0.f;
    float bias = clb[0];
    for (int b = 0; b < B_; ++b) {
      const float* f = flow + ((size_t)b*N_ + n)*T_;
      float acc = bias;
      #pragma unroll
      for (int t = 0; t < T_; ++t) acc += f[t]*clw[t];
      s += fmaxf(acc, 0.f);
    }
    mv[n] = s * (1.f/16.f);
  }
}

__global__ void k_fusemat(const float* __restrict__ mv, unsigned short* __restrict__ F)
{
  int idx = blockIdx.x*256 + threadIdx.x;
  int m = idx >> 10, n = idx & 1023;
  float x = 0.5f*(mv[m] + mv[n]);
  F[idx] = f2bf(1.f/(1.f + __expf(-x)));
}

// ---------------- launch ----------------
extern "C" void kernel_launch(void* const* d_in, const int* in_sizes, int n_in,
                              void* d_out, int out_size, void* d_ws, size_t ws_size,
                              hipStream_t stream)
{
  const float* flow = (const float*)d_in[0];
  const int*   day  = (const int*)d_in[1];
  const int*   week = (const int*)d_in[2];
  const float* semb = (const float*)d_in[3];
  const float* demb = (const float*)d_in[4];
  const float* wemb = (const float*)d_in[5];
  const float* gfsw = (const float*)d_in[6];
  const float* gfsb = (const float*)d_in[7];
  const float* gluw = (const float*)d_in[8];
  const float* glub = (const float*)d_in[9];
  const float* gcw  = (const float*)d_in[10];
  const float* gcA  = (const float*)d_in[11];
  const float* gcA2 = (const float*)d_in[12];
  const float* wi   = (const float*)d_in[13];
  const float* bi   = (const float*)d_in[14];
  const float* w1m  = (const float*)d_in[15];
  const float* b1m  = (const float*)d_in[16];
  const float* w1g  = (const float*)d_in[17];
  const float* b1g  = (const float*)d_in[18];
  const float* w2m  = (const float*)d_in[19];
  const float* b2m  = (const float*)d_in[20];
  const float* w2g  = (const float*)d_in[21];
  const float* b2g  = (const float*)d_in[22];
  const float* wfc  = (const float*)d_in[23];
  const float* bfc  = (const float*)d_in[24];
  const float* wq   = (const float*)d_in[25];
  const float* bq   = (const float*)d_in[26];
  const float* wk   = (const float*)d_in[27];
  const float* bk   = (const float*)d_in[28];
  const float* wv   = (const float*)d_in[29];
  const float* bv   = (const float*)d_in[30];
  const float* wo   = (const float*)d_in[31];
  const float* bo   = (const float*)d_in[32];
  const float* f1w  = (const float*)d_in[33];
  const float* f1b  = (const float*)d_in[34];
  const float* f2w  = (const float*)d_in[35];
  const float* f2b  = (const float*)d_in[36];
  const float* g1   = (const float*)d_in[37];
  const float* be1  = (const float*)d_in[38];
  const float* g2   = (const float*)d_in[39];
  const float* be2  = (const float*)d_in[40];
  const float* clw  = (const float*)d_in[41];
  const float* clb  = (const float*)d_in[42];

  float* out = (float*)d_out;
  char* ws = (char*)d_ws;
  unsigned short* Amat = (unsigned short*)ws;                               // 2 MB
  float* mv  = (float*)(ws + (size_t)2*1024*1024);                          // 64 KB region
  unsigned short* wTe = (unsigned short*)(ws + (size_t)2*1024*1024 + 64*1024); // 64 KB region
  unsigned short* wds = (unsigned short*)(ws + (size_t)2*1024*1024 + 128*1024); // 192 KB region
  unsigned short* wat = (unsigned short*)(ws + (size_t)2*1024*1024 + 320*1024); // 128 KB region
  unsigned short* xw  = (unsigned short*)(ws + (size_t)3*1024*1024);        // 24 MB
  unsigned short* xds = (unsigned short*)(ws + (size_t)28*1024*1024);       // 24 MB

  k_wprep_all<<<192, 256, 0, stream>>>(gfsw, gluw, gcw,
                                       wi, w1m, w1g, w2m, w2g, wfc,
                                       wq, wk, wv, wo, f1w, f2w,
                                       wTe, wds, wat);
  // xw = GLU(gfs_fc(embed)) @ gc_weight -> bf16   (full MFMA)
  k_embed3<<<BNT/128, 256, 0, stream>>>(flow, day, week, semb, demb, wemb,
                                        wTe, gfsb, glub, xw);
  // combined adjacency (bf16)
  k_aprep<<<N_, 256, 0, stream>>>(gcA, gcA2, Amat);
  // xds = relu(A @ xw) -> bf16
  dim3 gg(TD/128, N_/128, B_);
  k_gemm_mfma<1,1><<<gg, 256, 0, stream>>>(Amat, xw, xds, N_, TD);
  // ds block (MFMA) -> bf16, in-place on xds
  k_ds3<<<BN_/8, 256, 0, stream>>>(xds, wds, bi, b1m, b1g, b2m, b2g, bfc, xds);
  // y2 = attn+ffn block (MFMA) -> bf16 (reuse xw region)
  k_attn5<<<BN_/8, 512, 0, stream>>>(xds, wat, bq, bk, bv, bo, f1b, f2b,
                                     g1, be1, g2, be2, xw);
  // fuse matrix (bf16, reuse Amat region)
  k_mvec<<<N_/256, 256, 0, stream>>>(flow, clw, clb, mv);
  k_fusemat<<<(N_*N_)/256, 256, 0, stream>>>(mv, Amat);
  // out = fuse @ y2 -> d_out (fp32)
  k_gemm_mfma<0,0><<<gg, 256, 0, stream>>>(Amat, xw, out, N_, TD);
}